// Round 15
// baseline (169.649 us; speedup 1.0000x reference)
//
#include <hip/hip_runtime.h>
#include <math.h>

typedef __attribute__((ext_vector_type(8))) __bf16 bf16x8;
typedef __attribute__((ext_vector_type(8))) unsigned short us8;
typedef __attribute__((ext_vector_type(4))) unsigned short us4;
typedef __attribute__((ext_vector_type(4))) float f32x4;
typedef __attribute__((ext_vector_type(4))) int i32x4;
typedef unsigned int uint32;

#define EPSV 1e-5f

__device__ __forceinline__ float silu_f(float v) { return v / (1.f + __expf(-v)); }

__device__ __forceinline__ unsigned short f2bf(float f) {
  uint32 u = __builtin_bit_cast(uint32, f);
  u += 0x7fffu + ((u >> 16) & 1u);   // RNE
  return (unsigned short)(u >> 16);
}
__device__ __forceinline__ float bf2f(unsigned short h) {
  uint32 u = ((uint32)h) << 16;
  return __builtin_bit_cast(float, u);
}

// async global->LDS DMA, 16B per lane. LDS dest = wave-uniform base + lane*16.
__device__ __forceinline__ void gl_lds16(const void* g, void* l) {
  __builtin_amdgcn_global_load_lds(
      (const __attribute__((address_space(1))) unsigned int*)g,
      (__attribute__((address_space(3))) unsigned int*)l, 16, 0, 0);
}

// ---------------------------------------------------------------------------
// GEMM body BK=64, BN=64, BM=128.  4 waves, each 64x32 out, 2 k-steps/iter
// (16 MFMA/wave/iter).  LDS: A 1024 + B 512 chunks = 24KB/buf, dbuf 48KB.
// Chunk c: row16=c&15, kg=(c>>4)&3, ks=(c>>6)&1, sub=c>>7;
// koff = ks*32+kg*8; identity LDS chunk id; frag reads lane-linear per ks.
// k0/KL support split-K (conv tap = (k0+it*64)/CIN; exact since 64|CIN and
// kb%CIN + koff < CIN).
// EPI: 2 BN+SiLU->bf16 | 3 bias+BN->bf16 | 4 bias+SiLU->bf16
//      5 split val/om | 6 bias+x+y2 -> NCHW f32 | 7 raw bf16 (no bias)
// ---------------------------------------------------------------------------
template <int EPI, int CIN>
__device__ __forceinline__ void gemm_body64(
    int rb, int cb, int k0, int KL,
    const unsigned short* __restrict__ A, const unsigned short* __restrict__ Bw,
    const float* __restrict__ bias, int K, int Co, void* __restrict__ outv,
    const float* __restrict__ e0, const float* __restrict__ e1,
    const float* __restrict__ e2, const float* __restrict__ e3,
    const unsigned short* __restrict__ zpage, bf16x8* smem) {
  constexpr int CPB = 1536;
  const int t = threadIdx.x;
  const int lane = t & 63;
  const int wv = t >> 6;
  const int wr = wv >> 1, wc = wv & 1;

  f32x4 acc[4][2];
#pragma unroll
  for (int i = 0; i < 4; i++)
#pragma unroll
    for (int j = 0; j < 2; j++) acc[i][j] = (f32x4){0.f, 0.f, 0.f, 0.f};

  // A: 4 chunks/thread (1024 total), B: 2 chunks/thread (512 total)
  const unsigned short* Abase[4];
  int aprow[4], apcol[4], akoff[4];
#pragma unroll
  for (int i = 0; i < 4; i++) {
    int c = t + 256 * i;
    int row = (c >> 7) * 16 + (c & 15);
    int koff = ((c >> 6) & 1) * 32 + ((c >> 4) & 3) * 8;
    akoff[i] = koff;
    int grow = rb + row;
    if constexpr (CIN > 0) {
      int n = grow >> 12, p = grow & 4095;
      aprow[i] = p >> 6;
      apcol[i] = p & 63;
      Abase[i] = A + (size_t)n * 4096 * CIN;
    } else {
      Abase[i] = A + (size_t)grow * K + koff;
    }
  }
  const unsigned short* Bbase[2];
#pragma unroll
  for (int i = 0; i < 2; i++) {
    int c = t + 256 * i;
    int col = cb + (c >> 7) * 16 + (c & 15);
    int koff = ((c >> 6) & 1) * 32 + ((c >> 4) & 3) * 8;
    Bbase[i] = (col < Co) ? (Bw + (size_t)col * K + koff) : zpage;
  }
  auto addrA = [&](int i, int kb) -> const unsigned short* {
    if constexpr (CIN > 0) {
      int tap = kb / CIN;
      int ci = (kb & (CIN - 1)) + akoff[i];
      int dy = tap / 3 - 1, dx = tap % 3 - 1;
      int h = aprow[i] + dy, w = apcol[i] + dx;
      if (((unsigned)h < 64u) & ((unsigned)w < 64u))
        return &Abase[i][(size_t)(h * 64 + w) * CIN + ci];
      return zpage;
    } else {
      return Abase[i] + kb;
    }
  };
  auto stage = [&](int buf, int kb) {
    bf16x8* base = &smem[buf * CPB];
#pragma unroll
    for (int i = 0; i < 4; i++)
      gl_lds16(addrA(i, kb), (void*)&base[t + 256 * i]);
    gl_lds16((Bbase[0] == zpage) ? zpage : Bbase[0] + kb,
             (void*)&base[1024 + t]);
    gl_lds16((Bbase[1] == zpage) ? zpage : Bbase[1] + kb,
             (void*)&base[1024 + t + 256]);
  };

  const int nt = KL >> 6;
  stage(0, k0);
  __syncthreads();
  int cur = 0;
  for (int it = 0; it < nt; ++it) {
    if (it + 1 < nt) stage(cur ^ 1, k0 + ((it + 1) << 6));
    const bf16x8* Ab = &smem[cur * CPB];
    const bf16x8* Bb = Ab + 1024;
    __builtin_amdgcn_s_setprio(1);
#pragma unroll
    for (int ks = 0; ks < 2; ks++) {
      bf16x8 af[4], bfr[2];
#pragma unroll
      for (int mi = 0; mi < 4; mi++)
        af[mi] = Ab[((wr * 4 + mi) * 2 + ks) * 64 + lane];
#pragma unroll
      for (int ni = 0; ni < 2; ni++)
        bfr[ni] = Bb[((wc * 2 + ni) * 2 + ks) * 64 + lane];
#pragma unroll
      for (int mi = 0; mi < 4; mi++)
#pragma unroll
        for (int ni = 0; ni < 2; ni++)
          acc[mi][ni] = __builtin_amdgcn_mfma_f32_16x16x32_bf16(
              af[mi], bfr[ni], acc[mi][ni], 0, 0, 0);
    }
    __builtin_amdgcn_s_setprio(0);
    __syncthreads();
    cur ^= 1;
  }

  // ---- epilogue.  C/D: col = lane&15, row = (lane>>4)*4 + reg
  const int lr = lane & 15, kg4 = (lane >> 4) * 4;
#pragma unroll
  for (int mi = 0; mi < 4; mi++) {
#pragma unroll
    for (int ni = 0; ni < 2; ni++) {
      int gcol = cb + wc * 32 + ni * 16 + lr;
      if (gcol >= Co) continue;
      float bval, s = 1.f, tt = 0.f;
      if (EPI == 2 || EPI == 7) bval = 0.f;
      else if (EPI == 5) bval = (gcol < 256) ? bias[gcol] : e0[gcol - 256];
      else bval = bias[gcol];
      if (EPI == 2 || EPI == 3) {
        s = e0[gcol] * rsqrtf(e3[gcol] + EPSV);
        tt = e1[gcol] - e2[gcol] * s;
      }
      if (EPI == 6) {
        int grow0 = rb + wr * 64 + mi * 16 + kg4;
        int n = grow0 >> 12, p0 = grow0 & 4095;
        size_t oix = ((size_t)(n * 256 + gcol)) * 4096 + p0;
        f32x4 xv = *(const f32x4*)&((const float*)e0)[oix];
        const unsigned short* y2p = (const unsigned short*)e1;
        f32x4 ov;
#pragma unroll
        for (int j = 0; j < 4; j++) {
          float y2 = bf2f(y2p[((size_t)(n * 4096 + p0 + j)) * 256 + gcol]);
          ov[j] = acc[mi][ni][j] + bval + xv[j] + y2;
        }
        *(f32x4*)&((float*)outv)[oix] = ov;
        continue;
      }
#pragma unroll
      for (int j = 0; j < 4; j++) {
        int grow = rb + wr * 64 + mi * 16 + kg4 + j;
        float v = acc[mi][ni][j] + bval;
        if (EPI == 2) v = silu_f(v * s + tt);
        if (EPI == 3) v = v * s + tt;
        if (EPI == 4) v = silu_f(v);
        if (EPI == 5) {
          if (gcol < 256)
            ((unsigned short*)outv)[(size_t)grow * 256 + gcol] = f2bf(v);
          else
            ((float*)e1)[(size_t)grow * 216 + (gcol - 256)] = v;
        } else {
          ((unsigned short*)outv)[(size_t)grow * Co + gcol] = f2bf(v);
        }
      }
    }
  }
}

// ---------------------------------------------------------------------------
// DCNv4 core body v3: 8 pixels/block, phase-2 lanes carry 8 channels each.
// ---------------------------------------------------------------------------
__device__ __forceinline__ void dcn_body(
    int bid, const unsigned short* __restrict__ value,
    const float* __restrict__ om, unsigned short* __restrict__ out,
    void* smemraw) {
  f32x4* wgt = (f32x4*)smemraw;
  i32x4* adr = (i32x4*)((char*)smemraw + 576 * 16);
  const int n = bid >> 9;
  const int p0 = (bid & 511) * 8;
  const int t = threadIdx.x;

  for (int idx = t; idx < 576; idx += 256) {
    int pi = idx / 72;
    int gk = idx - pi * 72;
    int g = gk / 9, k = gk - g * 9;
    int p = p0 + pi;
    int h0 = p >> 6, w0 = p & 63;
    const float* omp = om + ((size_t)(n * 4096 + p)) * 216 + g * 27;
    float ox = omp[2 * k], oy = omp[2 * k + 1], mk = omp[18 + k];
    float px = (float)(w0 + (k % 3) - 1) + ox;
    float py = (float)(h0 + (k / 3) - 1) + oy;
    float x0f = floorf(px), y0f = floorf(py);
    float lx = px - x0f, ly = py - y0f;
    int x0 = (int)x0f, y0 = (int)y0f;
    int x1 = x0 + 1, y1 = y0 + 1;
    bool vx0 = (unsigned)x0 < 64u, vx1 = (unsigned)x1 < 64u;
    bool vy0 = (unsigned)y0 < 64u, vy1 = (unsigned)y1 < 64u;
    int cx0 = min(max(x0, 0), 63), cx1 = min(max(x1, 0), 63);
    int cy0 = min(max(y0, 0), 63), cy1 = min(max(y1, 0), 63);
    f32x4 w4;
    w4[0] = (1.f - ly) * (1.f - lx) * mk * (float)(vy0 && vx0);
    w4[1] = (1.f - ly) * lx * mk * (float)(vy0 && vx1);
    w4[2] = ly * (1.f - lx) * mk * (float)(vy1 && vx0);
    w4[3] = ly * lx * mk * (float)(vy1 && vx1);
    i32x4 a4;
    a4[0] = (cy0 * 64 + cx0) * 256;
    a4[1] = (cy0 * 64 + cx1) * 256;
    a4[2] = (cy1 * 64 + cx0) * 256;
    a4[3] = (cy1 * 64 + cx1) * 256;
    wgt[idx] = w4;
    adr[idx] = a4;
  }
  __syncthreads();

  const int pi = t >> 5;          // 0..7
  const int g = (t >> 2) & 7;     // 0..7
  const int l = t & 3;            // 0..3, 8 channels each
  const int p = p0 + pi;
  const unsigned short* vb = value + ((size_t)n * 4096) * 256 + g * 32 + l * 8;
  const int bix = (pi * 8 + g) * 9;
  float a[8] = {0.f, 0.f, 0.f, 0.f, 0.f, 0.f, 0.f, 0.f};
#pragma unroll
  for (int k = 0; k < 9; k++) {
    f32x4 wv = wgt[bix + k];
    i32x4 av = adr[bix + k];
    us8 q0 = *(const us8*)(vb + av[0]);
    us8 q1 = *(const us8*)(vb + av[1]);
    us8 q2 = *(const us8*)(vb + av[2]);
    us8 q3 = *(const us8*)(vb + av[3]);
#pragma unroll
    for (int j = 0; j < 8; j++)
      a[j] += wv[0] * bf2f(q0[j]) + wv[1] * bf2f(q1[j]) +
              wv[2] * bf2f(q2[j]) + wv[3] * bf2f(q3[j]);
  }
  us8 o;
#pragma unroll
  for (int j = 0; j < 8; j++) o[j] = f2bf(a[j]);
  *(us8*)&out[((size_t)(n * 4096 + p)) * 256 + g * 32 + l * 8] = o;
}

// ---------------------------------------------------------------------------
// PREP: NCHW->tokens transpose (0..1023) + conv weight cvt (coalesced 9-tap,
// 1024..1279) + plain cvts (1280..3543).
// ---------------------------------------------------------------------------
__global__ __launch_bounds__(256) void prep_k(
    const float* __restrict__ x, unsigned short* __restrict__ xt,
    const float* __restrict__ c1, unsigned short* __restrict__ o1,
    const float* __restrict__ c2, unsigned short* __restrict__ o2,
    const float* __restrict__ a0, unsigned short* __restrict__ b0,
    const float* __restrict__ a1, unsigned short* __restrict__ b1,
    const float* __restrict__ a2, unsigned short* __restrict__ b2,
    const float* __restrict__ a3, unsigned short* __restrict__ b3,
    const float* __restrict__ a4, unsigned short* __restrict__ b4,
    uint32* __restrict__ zp) {
  __shared__ float lds[64][65];
  int b = blockIdx.x;
  const int t = threadIdx.x;
  if (b == 0 && t < 32) zp[t] = 0u;
  if (b < 1024) {
    const int p0 = (b & 63) * 64, c0 = ((b >> 6) & 3) * 64, n = b >> 8;
    const int pp = t & 63, ccb = t >> 6;
    const float* xb = x + ((size_t)n * 256 + c0) * 4096 + p0;
#pragma unroll
    for (int i = 0; i < 16; i++) {
      int cc = ccb * 16 + i;
      lds[pp][cc] = xb[(size_t)cc * 4096 + pp];
    }
    __syncthreads();
#pragma unroll
    for (int i = 0; i < 2; i++) {
      int pp2 = (t >> 3) + i * 32;
      int c8 = (t & 7) * 8;
      us8 v;
#pragma unroll
      for (int j = 0; j < 8; j++) v[j] = f2bf(lds[pp2][c8 + j]);
      *(us8*)&xt[((size_t)(n * 4096 + p0 + pp2)) * 256 + c0 + c8] = v;
    }
    return;
  }
  if (b < 1152) {  // conv1 weights: thread per (co,ci), 9 contiguous taps
    int idx = (b - 1024) * 256 + t;
    int co = idx >> 8, ci = idx & 255;
    const float* src = c1 + (size_t)(co * 256 + ci) * 9;
#pragma unroll
    for (int tap = 0; tap < 9; tap++)
      o1[(size_t)(co * 9 + tap) * 256 + ci] = f2bf(src[tap]);
    return;
  }
  if (b < 1280) {  // conv2 weights
    int idx = (b - 1152) * 256 + t;
    int co = idx >> 7, ci = idx & 127;
    const float* src = c2 + (size_t)(co * 128 + ci) * 9;
#pragma unroll
    for (int tap = 0; tap < 9; tap++)
      o2[(size_t)(co * 9 + tap) * 128 + ci] = f2bf(src[tap]);
    return;
  }
  int idx = (b - 1280) * 256 + t;
  const float* s;
  unsigned short* d;
  int off;
  if (idx < 65536)       { s = a0; d = b0; off = idx; }
  else if (idx < 120832) { s = a1; d = b1; off = idx - 65536; }
  else if (idx < 186368) { s = a2; d = b2; off = idx - 120832; }
  else if (idx < 382976) { s = a3; d = b3; off = idx - 186368; }
  else if (idx < 579584) { s = a4; d = b4; off = idx - 382976; }
  else return;
  d[off] = f2bf(s[off]);
}

// ---------------------------------------------------------------------------
// S1 (2048 blocks, BK=64): 0..1023 conv1 split-K x4 (bf16 partials; 9 iters),
// 1024..2047 fused val/om projection (4 iters).
// ---------------------------------------------------------------------------
__global__ __launch_bounds__(256) void fused_s1(
    const unsigned short* __restrict__ xt,
    const unsigned short* __restrict__ wc1, unsigned short* __restrict__ part,
    const unsigned short* __restrict__ wval, const float* __restrict__ val_b,
    const float* __restrict__ om_b, float* __restrict__ omf,
    unsigned short* __restrict__ valt, const unsigned short* __restrict__ zpage) {
  __shared__ bf16x8 smem[3072];   // 48 KB
  int b = blockIdx.x;
  if (b < 1024) {
    int s = b >> 8, c = b & 255;
    int mt = c >> 1, ct = c & 1;
    gemm_body64<7, 256>(mt * 128, ct * 64, s * 576, 576, xt, wc1, nullptr,
                        2304, 128, part + (size_t)s * 2097152, nullptr,
                        nullptr, nullptr, nullptr, zpage, smem);
  } else {
    int v = b - 1024;
    gemm_body64<5, 0>((v >> 3) * 128, (v & 7) * 64, 0, 256, xt, wval, val_b,
                      256, 472, valt, om_b, (const float*)omf, nullptr,
                      nullptr, zpage, smem);
  }
}

// ---------------------------------------------------------------------------
// R (3072 blocks): 0..1023 y1 reduce+BN+SiLU, 1024..3071 dcn v3.
// ---------------------------------------------------------------------------
__global__ __launch_bounds__(256) void fused_r(
    const unsigned short* __restrict__ part, const float* __restrict__ g1,
    const float* __restrict__ bb1, const float* __restrict__ m1,
    const float* __restrict__ v1, unsigned short* __restrict__ y1t,
    const unsigned short* __restrict__ valt, const float* __restrict__ omf,
    unsigned short* __restrict__ dcnt) {
  __shared__ char rsm[18432];
  int b = blockIdx.x;
  if (b < 1024) {
    int g = b * 256 + threadIdx.x;
    int grow = g >> 4;
    int co8 = (g & 15) << 3;
    size_t base = (size_t)grow * 128 + co8;
    float sum[8] = {0.f, 0.f, 0.f, 0.f, 0.f, 0.f, 0.f, 0.f};
#pragma unroll
    for (int s = 0; s < 4; s++) {
      us8 pv = *(const us8*)&part[base + (size_t)s * 2097152];
#pragma unroll
      for (int j = 0; j < 8; j++) sum[j] += bf2f(pv[j]);
    }
    us8 o;
#pragma unroll
    for (int j = 0; j < 8; j++) {
      int co = co8 + j;
      float sc = g1[co] * rsqrtf(v1[co] + EPSV);
      float tt = bb1[co] - m1[co] * sc;
      o[j] = f2bf(silu_f(sum[j] * sc + tt));
    }
    *(us8*)&y1t[base] = o;
  } else {
    dcn_body(b - 1024, valt, omf, dcnt, (void*)rsm);
  }
}

// ---------------------------------------------------------------------------
// S2 (1024 blocks, BK=64): 0..511 conv2 (BN+SiLU), 512..1023 outp
// (bias+BN3 -> d1t).
// ---------------------------------------------------------------------------
__global__ __launch_bounds__(256) void fused_s2(
    const unsigned short* __restrict__ y1t,
    const unsigned short* __restrict__ wc2, const float* __restrict__ g2,
    const float* __restrict__ bb2, const float* __restrict__ m2,
    const float* __restrict__ v2, unsigned short* __restrict__ y2t,
    const unsigned short* __restrict__ dcnt, const unsigned short* __restrict__ woutp,
    const float* __restrict__ outp_b, const float* __restrict__ g3,
    const float* __restrict__ bb3, const float* __restrict__ m3,
    const float* __restrict__ v3, unsigned short* __restrict__ d1t,
    const unsigned short* __restrict__ zpage) {
  __shared__ bf16x8 smem[3072];   // 48 KB
  int b = blockIdx.x;
  if (b < 512) {
    gemm_body64<2, 128>((b >> 2) * 128, (b & 3) * 64, 0, 1152, y1t, wc2,
                        nullptr, 1152, 256, y2t, g2, bb2, m2, v2, zpage, smem);
  } else {
    b -= 512;
    gemm_body64<3, 0>((b >> 2) * 128, (b & 3) * 64, 0, 256, dcnt, woutp,
                      outp_b, 256, 256, d1t, g3, bb3, m3, v3, zpage, smem);
  }
}

// ---------------------------------------------------------------------------
// Standalone BK=64 GEMM wrapper (1D variant used for pw1 / pw2).
// ---------------------------------------------------------------------------
template <int EPI, int NCB>
__global__ __launch_bounds__(256) void gemm_k64(
    const unsigned short* __restrict__ A, const unsigned short* __restrict__ Bw,
    const float* __restrict__ bias, int K, int Co, void* __restrict__ outv,
    const float* __restrict__ e0, const float* __restrict__ e1,
    const float* __restrict__ e2, const float* __restrict__ e3,
    const unsigned short* __restrict__ zpage) {
  __shared__ bf16x8 smem[3072];
  int b = blockIdx.x;
  gemm_body64<EPI, 0>((b / NCB) * 128, (b % NCB) * 64, 0, K, A, Bw, bias,
                      K, Co, outv, e0, e1, e2, e3, zpage, smem);
}

// ---------------------------------------------------------------------------
extern "C" void kernel_launch(void* const* d_in, const int* in_sizes, int n_in,
                              void* d_out, int out_size, void* d_ws,
                              size_t ws_size, hipStream_t stream) {
  const float* x      = (const float*)d_in[0];
  const float* cv1_w  = (const float*)d_in[1];
  const float* cv1_g  = (const float*)d_in[2];
  const float* cv1_b  = (const float*)d_in[3];
  const float* cv1_m  = (const float*)d_in[4];
  const float* cv1_v  = (const float*)d_in[5];
  const float* cv2_w  = (const float*)d_in[6];
  const float* cv2_g  = (const float*)d_in[7];
  const float* cv2_b  = (const float*)d_in[8];
  const float* cv2_m  = (const float*)d_in[9];
  const float* cv2_v  = (const float*)d_in[10];
  const float* val_w  = (const float*)d_in[11];
  const float* val_b  = (const float*)d_in[12];
  const float* om_w   = (const float*)d_in[13];
  const float* om_b   = (const float*)d_in[14];
  const float* outp_w = (const float*)d_in[15];
  const float* outp_b = (const float*)d_in[16];
  const float* bn3_g  = (const float*)d_in[17];
  const float* bn3_b  = (const float*)d_in[18];
  const float* bn3_m  = (const float*)d_in[19];
  const float* bn3_v  = (const float*)d_in[20];
  const float* pw1_w  = (const float*)d_in[21];
  const float* pw1_b  = (const float*)d_in[22];
  const float* pw2_w  = (const float*)d_in[23];
  const float* pw2_b  = (const float*)d_in[24];
  float* out = (float*)d_out;

  char* w = (char*)d_ws;
  auto alloc = [&](size_t bytes) {
    char* p = w;
    w += (bytes + 255) & ~(size_t)255;
    return p;
  };
  unsigned short* xt    = (unsigned short*)alloc(16384ull * 256 * 2);
  unsigned short* y1t   = (unsigned short*)alloc(16384ull * 128 * 2);
  unsigned short* y2t   = (unsigned short*)alloc(16384ull * 256 * 2);
  unsigned short* valt  = (unsigned short*)alloc(16384ull * 256 * 2);
  float*          omf   = (float*)alloc(16384ull * 216 * 4);
  unsigned short* dcnt  = (unsigned short*)alloc(16384ull * 256 * 2);
  unsigned short* d1t   = (unsigned short*)alloc(16384ull * 256 * 2);  // 8 MB
  unsigned short* p1t   = (unsigned short*)alloc(16384ull * 768 * 2);  // 24 MB
  // conv1 split-K bf16 partials (16 MB) alias d1t+p1t (dead until S2/pw1):
  unsigned short* part = d1t;
  unsigned short* wc1   = (unsigned short*)alloc(128ull * 2304 * 2);
  unsigned short* wc2   = (unsigned short*)alloc(256ull * 1152 * 2);
  // wval and wom MUST be contiguous (fused val/om B-matrix, 472 x 256):
  unsigned short* wval  = (unsigned short*)alloc(256ull * 256 * 2);   // 256-mult
  unsigned short* wom   = (unsigned short*)alloc(216ull * 256 * 2);   // = wval + 65536
  unsigned short* woutp = (unsigned short*)alloc(256ull * 256 * 2);
  unsigned short* wpw1  = (unsigned short*)alloc(768ull * 256 * 2);
  unsigned short* wpw2  = (unsigned short*)alloc(256ull * 768 * 2);
  unsigned short* zpage = (unsigned short*)alloc(256);  // 64B zeros (+pad)

  // prep: tokens + weight conversions
  prep_k<<<3544, 256, 0, stream>>>(x, xt, cv1_w, wc1, cv2_w, wc2, val_w, wval,
                                   om_w, wom, outp_w, woutp, pw1_w, wpw1,
                                   pw2_w, wpw2, (uint32*)zpage);

  // S1: conv1 split-K4 (BK=64) -> bf16 partials ∪ val/om projection (BK=64)
  fused_s1<<<2048, 256, 0, stream>>>(xt, wc1, part, wval, val_b, om_b, omf,
                                     valt, zpage);

  // R: y1 reduce+BN+SiLU ∪ dcn core (us8, 8 pix/block)
  fused_r<<<3072, 256, 0, stream>>>(part, cv1_g, cv1_b, cv1_m, cv1_v, y1t,
                                    valt, omf, dcnt);

  // S2: conv2 (BK=64) ∪ outp (BK=64)
  fused_s2<<<1024, 256, 0, stream>>>(y1t, wc2, cv2_g, cv2_b, cv2_m, cv2_v, y2t,
                                     dcnt, woutp, outp_b, bn3_g, bn3_b, bn3_m,
                                     bn3_v, d1t, zpage);

  // pw1 (1536 blocks, BK=64), pw2 + residual (512 blocks, BK=64)
  gemm_k64<4, 12><<<1536, 256, 0, stream>>>(
      d1t, wpw1, pw1_b, 256, 768, p1t, nullptr, nullptr, nullptr, nullptr, zpage);
  gemm_k64<6, 4><<<512, 256, 0, stream>>>(
      p1t, wpw2, pw2_b, 768, 256, out, x, (const float*)y2t, nullptr, nullptr, zpage);
}

// Round 16
// 156.033 us; speedup vs baseline: 1.0873x; 1.0873x over previous
//
#include <hip/hip_runtime.h>
#include <math.h>

typedef __attribute__((ext_vector_type(8))) __bf16 bf16x8;
typedef __attribute__((ext_vector_type(8))) unsigned short us8;
typedef __attribute__((ext_vector_type(4))) unsigned short us4;
typedef __attribute__((ext_vector_type(4))) float f32x4;
typedef __attribute__((ext_vector_type(4))) int i32x4;
typedef unsigned int uint32;

#define EPSV 1e-5f

__device__ __forceinline__ float silu_f(float v) { return v / (1.f + __expf(-v)); }

__device__ __forceinline__ unsigned short f2bf(float f) {
  uint32 u = __builtin_bit_cast(uint32, f);
  u += 0x7fffu + ((u >> 16) & 1u);   // RNE
  return (unsigned short)(u >> 16);
}
__device__ __forceinline__ float bf2f(unsigned short h) {
  uint32 u = ((uint32)h) << 16;
  return __builtin_bit_cast(float, u);
}

// async global->LDS DMA, 16B per lane. LDS dest = wave-uniform base + lane*16.
__device__ __forceinline__ void gl_lds16(const void* g, void* l) {
  __builtin_amdgcn_global_load_lds(
      (const __attribute__((address_space(1))) unsigned int*)g,
      (__attribute__((address_space(3))) unsigned int*)l, 16, 0, 0);
}

// ---------------------------------------------------------------------------
// GEMM body (BK=32).  BM=128; BN in {128, 64}.  4 waves.  R12/R14-proven.
// EPI: 2 BN+SiLU->bf16 | 3 bias+BN->bf16 | 4 bias+SiLU->bf16
//      5 split val/om (om -> bf16) | 6 bias+x+y2 -> NCHW f32 | 7 raw bf16
// ---------------------------------------------------------------------------
template <int EPI, int CIN, int BN>
__device__ __forceinline__ void gemm_body(
    int rb, int cb, int k0, int KL,
    const unsigned short* __restrict__ A, const unsigned short* __restrict__ Bw,
    const float* __restrict__ bias, int K, int Co, void* __restrict__ outv,
    const float* __restrict__ e0, const float* __restrict__ e1,
    const float* __restrict__ e2, const float* __restrict__ e3,
    const unsigned short* __restrict__ zpage, bf16x8* smem) {
  constexpr int NFR = BN / 32;
  constexpr int NB = BN / 64;
  constexpr int CPB = 512 + BN * 4;
  const int t = threadIdx.x;
  const int lane = t & 63;
  const int wv = t >> 6;
  const int wr = wv >> 1, wc = wv & 1;

  f32x4 acc[4][NFR];
#pragma unroll
  for (int i = 0; i < 4; i++)
#pragma unroll
    for (int j = 0; j < NFR; j++) acc[i][j] = (f32x4){0.f, 0.f, 0.f, 0.f};

  const unsigned short* Abase[2];
  int aprow[2], apcol[2], akoff[2];
#pragma unroll
  for (int i = 0; i < 2; i++) {
    int c = t + 256 * i;
    int row = (c >> 6) * 16 + (c & 15);
    int koff = ((c >> 4) & 3) * 8;
    akoff[i] = koff;
    int grow = rb + row;
    if constexpr (CIN > 0) {
      int n = grow >> 12, p = grow & 4095;
      aprow[i] = p >> 6;
      apcol[i] = p & 63;
      Abase[i] = A + (size_t)n * 4096 * CIN;
    } else {
      Abase[i] = A + (size_t)grow * K + koff;
    }
  }
  const unsigned short* Bbase[NB];
#pragma unroll
  for (int i = 0; i < NB; i++) {
    int c = t + 256 * i;
    int col = cb + (c >> 6) * 16 + (c & 15);
    int koff = ((c >> 4) & 3) * 8;
    Bbase[i] = (col < Co) ? (Bw + (size_t)col * K + koff) : zpage;
  }
  auto addrA = [&](int i, int kb) -> const unsigned short* {
    if constexpr (CIN > 0) {
      int tap = kb / CIN;
      int ci = (kb & (CIN - 1)) + akoff[i];
      int dy = tap / 3 - 1, dx = tap % 3 - 1;
      int h = aprow[i] + dy, w = apcol[i] + dx;
      if (((unsigned)h < 64u) & ((unsigned)w < 64u))
        return &Abase[i][(size_t)(h * 64 + w) * CIN + ci];
      return zpage;
    } else {
      return Abase[i] + kb;
    }
  };
  auto stage = [&](int buf, int kb) {
    bf16x8* base = &smem[buf * CPB];
    gl_lds16(addrA(0, kb), (void*)&base[t]);
    gl_lds16(addrA(1, kb), (void*)&base[t + 256]);
    gl_lds16((Bbase[0] == zpage) ? zpage : Bbase[0] + kb, (void*)&base[512 + t]);
    if constexpr (NB == 2)
      gl_lds16((Bbase[1] == zpage) ? zpage : Bbase[1] + kb,
               (void*)&base[512 + t + 256]);
  };

  const int nt = KL >> 5;
  stage(0, k0);
  __syncthreads();
  int cur = 0;
  for (int it = 0; it < nt; ++it) {
    if (it + 1 < nt) stage(cur ^ 1, k0 + ((it + 1) << 5));
    const bf16x8* Ab = &smem[cur * CPB];
    const bf16x8* Bb = Ab + 512;
    bf16x8 af[4], bfr[NFR];
#pragma unroll
    for (int mi = 0; mi < 4; mi++) af[mi] = Ab[(wr * 4 + mi) * 64 + lane];
#pragma unroll
    for (int ni = 0; ni < NFR; ni++) bfr[ni] = Bb[(wc * NFR + ni) * 64 + lane];
    __builtin_amdgcn_s_setprio(1);
#pragma unroll
    for (int mi = 0; mi < 4; mi++)
#pragma unroll
      for (int ni = 0; ni < NFR; ni++)
        acc[mi][ni] = __builtin_amdgcn_mfma_f32_16x16x32_bf16(af[mi], bfr[ni],
                                                              acc[mi][ni], 0, 0, 0);
    __builtin_amdgcn_s_setprio(0);
    __syncthreads();
    cur ^= 1;
  }

  // ---- epilogue.  C/D: col = lane&15, row = (lane>>4)*4 + reg
  const int lr = lane & 15, kg4 = (lane >> 4) * 4;
#pragma unroll
  for (int mi = 0; mi < 4; mi++) {
#pragma unroll
    for (int ni = 0; ni < NFR; ni++) {
      int gcol = cb + wc * (BN / 2) + ni * 16 + lr;
      if (gcol >= Co) continue;
      float bval, s = 1.f, tt = 0.f;
      if (EPI == 2 || EPI == 7) bval = 0.f;
      else if (EPI == 5) bval = (gcol < 256) ? bias[gcol] : e0[gcol - 256];
      else bval = bias[gcol];
      if (EPI == 2 || EPI == 3) {
        s = e0[gcol] * rsqrtf(e3[gcol] + EPSV);
        tt = e1[gcol] - e2[gcol] * s;
      }
      if (EPI == 6) {
        int grow0 = rb + wr * 64 + mi * 16 + kg4;
        int n = grow0 >> 12, p0 = grow0 & 4095;
        size_t oix = ((size_t)(n * 256 + gcol)) * 4096 + p0;
        f32x4 xv = *(const f32x4*)&((const float*)e0)[oix];
        const unsigned short* y2p = (const unsigned short*)e1;
        f32x4 ov;
#pragma unroll
        for (int j = 0; j < 4; j++) {
          float y2 = bf2f(y2p[((size_t)(n * 4096 + p0 + j)) * 256 + gcol]);
          ov[j] = acc[mi][ni][j] + bval + xv[j] + y2;
        }
        *(f32x4*)&((float*)outv)[oix] = ov;
        continue;
      }
#pragma unroll
      for (int j = 0; j < 4; j++) {
        int grow = rb + wr * 64 + mi * 16 + kg4 + j;
        float v = acc[mi][ni][j] + bval;
        if (EPI == 2) v = silu_f(v * s + tt);
        if (EPI == 3) v = v * s + tt;
        if (EPI == 4) v = silu_f(v);
        if (EPI == 5) {
          if (gcol < 256)
            ((unsigned short*)outv)[(size_t)grow * 256 + gcol] = f2bf(v);
          else
            ((unsigned short*)e1)[(size_t)grow * 216 + (gcol - 256)] = f2bf(v);
        } else {
          ((unsigned short*)outv)[(size_t)grow * Co + gcol] = f2bf(v);
        }
      }
    }
  }
}

// ---------------------------------------------------------------------------
// GEMM body BK=64, BN=64, BM=128.  4 waves, each 64x32 out, 2 k-steps/iter
// (16 MFMA/wave/iter).  LDS 24KB/buf, dbuf 48KB.  R14-proven for conv2/outp/
// pw2 (single-col-tile-per-A-slab shapes only — BN=64 doubles A refetch on
// wide outputs; keep conv1/val-om/pw1 on the BK=32 BN=128 body).
// EPI: 2 BN+SiLU->bf16 | 3 bias+BN->bf16 | 6 bias+x+y2 -> NCHW f32
// ---------------------------------------------------------------------------
template <int EPI, int CIN>
__device__ __forceinline__ void gemm_body64(
    int rb, int cb, int k0, int KL,
    const unsigned short* __restrict__ A, const unsigned short* __restrict__ Bw,
    const float* __restrict__ bias, int K, int Co, void* __restrict__ outv,
    const float* __restrict__ e0, const float* __restrict__ e1,
    const float* __restrict__ e2, const float* __restrict__ e3,
    const unsigned short* __restrict__ zpage, bf16x8* smem) {
  constexpr int CPB = 1536;
  const int t = threadIdx.x;
  const int lane = t & 63;
  const int wv = t >> 6;
  const int wr = wv >> 1, wc = wv & 1;

  f32x4 acc[4][2];
#pragma unroll
  for (int i = 0; i < 4; i++)
#pragma unroll
    for (int j = 0; j < 2; j++) acc[i][j] = (f32x4){0.f, 0.f, 0.f, 0.f};

  const unsigned short* Abase[4];
  int aprow[4], apcol[4], akoff[4];
#pragma unroll
  for (int i = 0; i < 4; i++) {
    int c = t + 256 * i;
    int row = (c >> 7) * 16 + (c & 15);
    int koff = ((c >> 6) & 1) * 32 + ((c >> 4) & 3) * 8;
    akoff[i] = koff;
    int grow = rb + row;
    if constexpr (CIN > 0) {
      int n = grow >> 12, p = grow & 4095;
      aprow[i] = p >> 6;
      apcol[i] = p & 63;
      Abase[i] = A + (size_t)n * 4096 * CIN;
    } else {
      Abase[i] = A + (size_t)grow * K + koff;
    }
  }
  const unsigned short* Bbase[2];
#pragma unroll
  for (int i = 0; i < 2; i++) {
    int c = t + 256 * i;
    int col = cb + (c >> 7) * 16 + (c & 15);
    int koff = ((c >> 6) & 1) * 32 + ((c >> 4) & 3) * 8;
    Bbase[i] = (col < Co) ? (Bw + (size_t)col * K + koff) : zpage;
  }
  auto addrA = [&](int i, int kb) -> const unsigned short* {
    if constexpr (CIN > 0) {
      int tap = kb / CIN;
      int ci = (kb & (CIN - 1)) + akoff[i];
      int dy = tap / 3 - 1, dx = tap % 3 - 1;
      int h = aprow[i] + dy, w = apcol[i] + dx;
      if (((unsigned)h < 64u) & ((unsigned)w < 64u))
        return &Abase[i][(size_t)(h * 64 + w) * CIN + ci];
      return zpage;
    } else {
      return Abase[i] + kb;
    }
  };
  auto stage = [&](int buf, int kb) {
    bf16x8* base = &smem[buf * CPB];
#pragma unroll
    for (int i = 0; i < 4; i++)
      gl_lds16(addrA(i, kb), (void*)&base[t + 256 * i]);
    gl_lds16((Bbase[0] == zpage) ? zpage : Bbase[0] + kb,
             (void*)&base[1024 + t]);
    gl_lds16((Bbase[1] == zpage) ? zpage : Bbase[1] + kb,
             (void*)&base[1024 + t + 256]);
  };

  const int nt = KL >> 6;
  stage(0, k0);
  __syncthreads();
  int cur = 0;
  for (int it = 0; it < nt; ++it) {
    if (it + 1 < nt) stage(cur ^ 1, k0 + ((it + 1) << 6));
    const bf16x8* Ab = &smem[cur * CPB];
    const bf16x8* Bb = Ab + 1024;
    __builtin_amdgcn_s_setprio(1);
#pragma unroll
    for (int ks = 0; ks < 2; ks++) {
      bf16x8 af[4], bfr[2];
#pragma unroll
      for (int mi = 0; mi < 4; mi++)
        af[mi] = Ab[((wr * 4 + mi) * 2 + ks) * 64 + lane];
#pragma unroll
      for (int ni = 0; ni < 2; ni++)
        bfr[ni] = Bb[((wc * 2 + ni) * 2 + ks) * 64 + lane];
#pragma unroll
      for (int mi = 0; mi < 4; mi++)
#pragma unroll
        for (int ni = 0; ni < 2; ni++)
          acc[mi][ni] = __builtin_amdgcn_mfma_f32_16x16x32_bf16(
              af[mi], bfr[ni], acc[mi][ni], 0, 0, 0);
    }
    __builtin_amdgcn_s_setprio(0);
    __syncthreads();
    cur ^= 1;
  }

  // ---- epilogue (C/D: col = lane&15, row = (lane>>4)*4 + reg)
  const int lr = lane & 15, kg4 = (lane >> 4) * 4;
#pragma unroll
  for (int mi = 0; mi < 4; mi++) {
#pragma unroll
    for (int ni = 0; ni < 2; ni++) {
      int gcol = cb + wc * 32 + ni * 16 + lr;
      if (gcol >= Co) continue;
      float bval, s = 1.f, tt = 0.f;
      if (EPI == 2) bval = 0.f;
      else bval = bias[gcol];
      if (EPI == 2 || EPI == 3) {
        s = e0[gcol] * rsqrtf(e3[gcol] + EPSV);
        tt = e1[gcol] - e2[gcol] * s;
      }
      if (EPI == 6) {
        int grow0 = rb + wr * 64 + mi * 16 + kg4;
        int n = grow0 >> 12, p0 = grow0 & 4095;
        size_t oix = ((size_t)(n * 256 + gcol)) * 4096 + p0;
        f32x4 xv = *(const f32x4*)&((const float*)e0)[oix];
        const unsigned short* y2p = (const unsigned short*)e1;
        f32x4 ov;
#pragma unroll
        for (int j = 0; j < 4; j++) {
          float y2 = bf2f(y2p[((size_t)(n * 4096 + p0 + j)) * 256 + gcol]);
          ov[j] = acc[mi][ni][j] + bval + xv[j] + y2;
        }
        *(f32x4*)&((float*)outv)[oix] = ov;
        continue;
      }
#pragma unroll
      for (int j = 0; j < 4; j++) {
        int grow = rb + wr * 64 + mi * 16 + kg4 + j;
        float v = acc[mi][ni][j] + bval;
        if (EPI == 2) v = silu_f(v * s + tt);
        if (EPI == 3) v = v * s + tt;
        ((unsigned short*)outv)[(size_t)grow * Co + gcol] = f2bf(v);
      }
    }
  }
}

// ---------------------------------------------------------------------------
// DCNv4 core body v3: 8 pixels/block, phase-2 lanes carry 8 channels each.
// om is now bf16 (N,4096,216).
// ---------------------------------------------------------------------------
__device__ __forceinline__ void dcn_body(
    int bid, const unsigned short* __restrict__ value,
    const unsigned short* __restrict__ om, unsigned short* __restrict__ out,
    void* smemraw) {
  f32x4* wgt = (f32x4*)smemraw;
  i32x4* adr = (i32x4*)((char*)smemraw + 576 * 16);
  const int n = bid >> 9;
  const int p0 = (bid & 511) * 8;
  const int t = threadIdx.x;

  for (int idx = t; idx < 576; idx += 256) {
    int pi = idx / 72;
    int gk = idx - pi * 72;
    int g = gk / 9, k = gk - g * 9;
    int p = p0 + pi;
    int h0 = p >> 6, w0 = p & 63;
    const unsigned short* omp = om + ((size_t)(n * 4096 + p)) * 216 + g * 27;
    float ox = bf2f(omp[2 * k]), oy = bf2f(omp[2 * k + 1]);
    float mk = bf2f(omp[18 + k]);
    float px = (float)(w0 + (k % 3) - 1) + ox;
    float py = (float)(h0 + (k / 3) - 1) + oy;
    float x0f = floorf(px), y0f = floorf(py);
    float lx = px - x0f, ly = py - y0f;
    int x0 = (int)x0f, y0 = (int)y0f;
    int x1 = x0 + 1, y1 = y0 + 1;
    bool vx0 = (unsigned)x0 < 64u, vx1 = (unsigned)x1 < 64u;
    bool vy0 = (unsigned)y0 < 64u, vy1 = (unsigned)y1 < 64u;
    int cx0 = min(max(x0, 0), 63), cx1 = min(max(x1, 0), 63);
    int cy0 = min(max(y0, 0), 63), cy1 = min(max(y1, 0), 63);
    f32x4 w4;
    w4[0] = (1.f - ly) * (1.f - lx) * mk * (float)(vy0 && vx0);
    w4[1] = (1.f - ly) * lx * mk * (float)(vy0 && vx1);
    w4[2] = ly * (1.f - lx) * mk * (float)(vy1 && vx0);
    w4[3] = ly * lx * mk * (float)(vy1 && vx1);
    i32x4 a4;
    a4[0] = (cy0 * 64 + cx0) * 256;
    a4[1] = (cy0 * 64 + cx1) * 256;
    a4[2] = (cy1 * 64 + cx0) * 256;
    a4[3] = (cy1 * 64 + cx1) * 256;
    wgt[idx] = w4;
    adr[idx] = a4;
  }
  __syncthreads();

  const int pi = t >> 5;          // 0..7
  const int g = (t >> 2) & 7;     // 0..7
  const int l = t & 3;            // 0..3, 8 channels each
  const int p = p0 + pi;
  const unsigned short* vb = value + ((size_t)n * 4096) * 256 + g * 32 + l * 8;
  const int bix = (pi * 8 + g) * 9;
  float a[8] = {0.f, 0.f, 0.f, 0.f, 0.f, 0.f, 0.f, 0.f};
#pragma unroll
  for (int k = 0; k < 9; k++) {
    f32x4 wv = wgt[bix + k];
    i32x4 av = adr[bix + k];
    us8 q0 = *(const us8*)(vb + av[0]);
    us8 q1 = *(const us8*)(vb + av[1]);
    us8 q2 = *(const us8*)(vb + av[2]);
    us8 q3 = *(const us8*)(vb + av[3]);
#pragma unroll
    for (int j = 0; j < 8; j++)
      a[j] += wv[0] * bf2f(q0[j]) + wv[1] * bf2f(q1[j]) +
              wv[2] * bf2f(q2[j]) + wv[3] * bf2f(q3[j]);
  }
  us8 o;
#pragma unroll
  for (int j = 0; j < 8; j++) o[j] = f2bf(a[j]);
  *(us8*)&out[((size_t)(n * 4096 + p)) * 256 + g * 32 + l * 8] = o;
}

// ---------------------------------------------------------------------------
// PREP: NCHW->tokens transpose (0..1023) + conv weight cvt (coalesced 9-tap,
// 1024..1279) + plain cvts (1280..3543).
// ---------------------------------------------------------------------------
__global__ __launch_bounds__(256) void prep_k(
    const float* __restrict__ x, unsigned short* __restrict__ xt,
    const float* __restrict__ c1, unsigned short* __restrict__ o1,
    const float* __restrict__ c2, unsigned short* __restrict__ o2,
    const float* __restrict__ a0, unsigned short* __restrict__ b0,
    const float* __restrict__ a1, unsigned short* __restrict__ b1,
    const float* __restrict__ a2, unsigned short* __restrict__ b2,
    const float* __restrict__ a3, unsigned short* __restrict__ b3,
    const float* __restrict__ a4, unsigned short* __restrict__ b4,
    uint32* __restrict__ zp) {
  __shared__ float lds[64][65];
  int b = blockIdx.x;
  const int t = threadIdx.x;
  if (b == 0 && t < 32) zp[t] = 0u;
  if (b < 1024) {
    const int p0 = (b & 63) * 64, c0 = ((b >> 6) & 3) * 64, n = b >> 8;
    const int pp = t & 63, ccb = t >> 6;
    const float* xb = x + ((size_t)n * 256 + c0) * 4096 + p0;
#pragma unroll
    for (int i = 0; i < 16; i++) {
      int cc = ccb * 16 + i;
      lds[pp][cc] = xb[(size_t)cc * 4096 + pp];
    }
    __syncthreads();
#pragma unroll
    for (int i = 0; i < 2; i++) {
      int pp2 = (t >> 3) + i * 32;
      int c8 = (t & 7) * 8;
      us8 v;
#pragma unroll
      for (int j = 0; j < 8; j++) v[j] = f2bf(lds[pp2][c8 + j]);
      *(us8*)&xt[((size_t)(n * 4096 + p0 + pp2)) * 256 + c0 + c8] = v;
    }
    return;
  }
  if (b < 1152) {  // conv1 weights: thread per (co,ci), 9 contiguous taps
    int idx = (b - 1024) * 256 + t;
    int co = idx >> 8, ci = idx & 255;
    const float* src = c1 + (size_t)(co * 256 + ci) * 9;
#pragma unroll
    for (int tap = 0; tap < 9; tap++)
      o1[(size_t)(co * 9 + tap) * 256 + ci] = f2bf(src[tap]);
    return;
  }
  if (b < 1280) {  // conv2 weights
    int idx = (b - 1152) * 256 + t;
    int co = idx >> 7, ci = idx & 127;
    const float* src = c2 + (size_t)(co * 128 + ci) * 9;
#pragma unroll
    for (int tap = 0; tap < 9; tap++)
      o2[(size_t)(co * 9 + tap) * 128 + ci] = f2bf(src[tap]);
    return;
  }
  int idx = (b - 1280) * 256 + t;
  const float* s;
  unsigned short* d;
  int off;
  if (idx < 65536)       { s = a0; d = b0; off = idx; }
  else if (idx < 120832) { s = a1; d = b1; off = idx - 65536; }
  else if (idx < 186368) { s = a2; d = b2; off = idx - 120832; }
  else if (idx < 382976) { s = a3; d = b3; off = idx - 186368; }
  else if (idx < 579584) { s = a4; d = b4; off = idx - 382976; }
  else return;
  d[off] = f2bf(s[off]);
}

// ---------------------------------------------------------------------------
// S1 (1024 blocks, BK=32 BN=128): 0..511 conv1 split-K x4 (bf16 partials),
// 512..1023 fused val/om projection (om -> bf16).
// ---------------------------------------------------------------------------
__global__ __launch_bounds__(256) void fused_s1(
    const unsigned short* __restrict__ xt,
    const unsigned short* __restrict__ wc1, unsigned short* __restrict__ part,
    const unsigned short* __restrict__ wval, const float* __restrict__ val_b,
    const float* __restrict__ om_b, unsigned short* __restrict__ omf,
    unsigned short* __restrict__ valt, const unsigned short* __restrict__ zpage) {
  __shared__ bf16x8 smem[2048];
  int b = blockIdx.x;
  if (b < 512) {
    int s = b >> 7, mt = b & 127;
    gemm_body<7, 256, 128>(mt * 128, 0, s * 576, 576, xt, wc1, nullptr, 2304,
                           128, part + (size_t)s * 2097152, nullptr, nullptr,
                           nullptr, nullptr, zpage, smem);
  } else {
    b -= 512;
    gemm_body<5, 0, 128>((b >> 2) * 128, (b & 3) * 128, 0, 256, xt, wval, val_b,
                         256, 472, valt, om_b, (const float*)(const void*)omf,
                         nullptr, nullptr, zpage, smem);
  }
}

// ---------------------------------------------------------------------------
// R (3072 blocks): 0..1023 y1 reduce+BN+SiLU, 1024..3071 dcn v3.
// ---------------------------------------------------------------------------
__global__ __launch_bounds__(256) void fused_r(
    const unsigned short* __restrict__ part, const float* __restrict__ g1,
    const float* __restrict__ bb1, const float* __restrict__ m1,
    const float* __restrict__ v1, unsigned short* __restrict__ y1t,
    const unsigned short* __restrict__ valt, const unsigned short* __restrict__ omf,
    unsigned short* __restrict__ dcnt) {
  __shared__ char rsm[18432];
  int b = blockIdx.x;
  if (b < 1024) {
    int g = b * 256 + threadIdx.x;
    int grow = g >> 4;
    int co8 = (g & 15) << 3;
    size_t base = (size_t)grow * 128 + co8;
    float sum[8] = {0.f, 0.f, 0.f, 0.f, 0.f, 0.f, 0.f, 0.f};
#pragma unroll
    for (int s = 0; s < 4; s++) {
      us8 pv = *(const us8*)&part[base + (size_t)s * 2097152];
#pragma unroll
      for (int j = 0; j < 8; j++) sum[j] += bf2f(pv[j]);
    }
    us8 o;
#pragma unroll
    for (int j = 0; j < 8; j++) {
      int co = co8 + j;
      float sc = g1[co] * rsqrtf(v1[co] + EPSV);
      float tt = bb1[co] - m1[co] * sc;
      o[j] = f2bf(silu_f(sum[j] * sc + tt));
    }
    *(us8*)&y1t[base] = o;
  } else {
    dcn_body(b - 1024, valt, omf, dcnt, (void*)rsm);
  }
}

// ---------------------------------------------------------------------------
// S2 (1024 blocks, BK=64): 0..511 conv2 (BN+SiLU), 512..1023 outp
// (bias+BN3 -> d1t).
// ---------------------------------------------------------------------------
__global__ __launch_bounds__(256) void fused_s2(
    const unsigned short* __restrict__ y1t,
    const unsigned short* __restrict__ wc2, const float* __restrict__ g2,
    const float* __restrict__ bb2, const float* __restrict__ m2,
    const float* __restrict__ v2, unsigned short* __restrict__ y2t,
    const unsigned short* __restrict__ dcnt, const unsigned short* __restrict__ woutp,
    const float* __restrict__ outp_b, const float* __restrict__ g3,
    const float* __restrict__ bb3, const float* __restrict__ m3,
    const float* __restrict__ v3, unsigned short* __restrict__ d1t,
    const unsigned short* __restrict__ zpage) {
  __shared__ bf16x8 smem[3072];   // 48 KB
  int b = blockIdx.x;
  if (b < 512) {
    gemm_body64<2, 128>((b >> 2) * 128, (b & 3) * 64, 0, 1152, y1t, wc2,
                        nullptr, 1152, 256, y2t, g2, bb2, m2, v2, zpage, smem);
  } else {
    b -= 512;
    gemm_body64<3, 0>((b >> 2) * 128, (b & 3) * 64, 0, 256, dcnt, woutp,
                      outp_b, 256, 256, d1t, g3, bb3, m3, v3, zpage, smem);
  }
}

// ---------------------------------------------------------------------------
// Standalone GEMM wrappers.
// ---------------------------------------------------------------------------
template <int EPI, int CIN, int BN>
__global__ __launch_bounds__(256) void gemm_k(
    const unsigned short* __restrict__ A, const unsigned short* __restrict__ Bw,
    const float* __restrict__ bias, int K, int Co, void* __restrict__ outv,
    const float* __restrict__ e0, const float* __restrict__ e1,
    const float* __restrict__ e2, const float* __restrict__ e3,
    const unsigned short* __restrict__ zpage) {
  __shared__ bf16x8 smem[2 * (512 + BN * 4)];
  gemm_body<EPI, CIN, BN>(blockIdx.y * 128, blockIdx.x * BN, 0, K, A, Bw, bias,
                          K, Co, outv, e0, e1, e2, e3, zpage, smem);
}

template <int EPI>
__global__ __launch_bounds__(256) void gemm_k64(
    const unsigned short* __restrict__ A, const unsigned short* __restrict__ Bw,
    const float* __restrict__ bias, int K, int Co, void* __restrict__ outv,
    const float* __restrict__ e0, const float* __restrict__ e1,
    const float* __restrict__ e2, const float* __restrict__ e3,
    const unsigned short* __restrict__ zpage) {
  __shared__ bf16x8 smem[3072];
  gemm_body64<EPI, 0>(blockIdx.y * 128, blockIdx.x * 64, 0, K, A, Bw, bias,
                      K, Co, outv, e0, e1, e2, e3, zpage, smem);
}

// ---------------------------------------------------------------------------
extern "C" void kernel_launch(void* const* d_in, const int* in_sizes, int n_in,
                              void* d_out, int out_size, void* d_ws,
                              size_t ws_size, hipStream_t stream) {
  const float* x      = (const float*)d_in[0];
  const float* cv1_w  = (const float*)d_in[1];
  const float* cv1_g  = (const float*)d_in[2];
  const float* cv1_b  = (const float*)d_in[3];
  const float* cv1_m  = (const float*)d_in[4];
  const float* cv1_v  = (const float*)d_in[5];
  const float* cv2_w  = (const float*)d_in[6];
  const float* cv2_g  = (const float*)d_in[7];
  const float* cv2_b  = (const float*)d_in[8];
  const float* cv2_m  = (const float*)d_in[9];
  const float* cv2_v  = (const float*)d_in[10];
  const float* val_w  = (const float*)d_in[11];
  const float* val_b  = (const float*)d_in[12];
  const float* om_w   = (const float*)d_in[13];
  const float* om_b   = (const float*)d_in[14];
  const float* outp_w = (const float*)d_in[15];
  const float* outp_b = (const float*)d_in[16];
  const float* bn3_g  = (const float*)d_in[17];
  const float* bn3_b  = (const float*)d_in[18];
  const float* bn3_m  = (const float*)d_in[19];
  const float* bn3_v  = (const float*)d_in[20];
  const float* pw1_w  = (const float*)d_in[21];
  const float* pw1_b  = (const float*)d_in[22];
  const float* pw2_w  = (const float*)d_in[23];
  const float* pw2_b  = (const float*)d_in[24];
  float* out = (float*)d_out;

  char* w = (char*)d_ws;
  auto alloc = [&](size_t bytes) {
    char* p = w;
    w += (bytes + 255) & ~(size_t)255;
    return p;
  };
  unsigned short* xt    = (unsigned short*)alloc(16384ull * 256 * 2);
  unsigned short* y1t   = (unsigned short*)alloc(16384ull * 128 * 2);
  unsigned short* y2t   = (unsigned short*)alloc(16384ull * 256 * 2);
  unsigned short* valt  = (unsigned short*)alloc(16384ull * 256 * 2);
  unsigned short* omf   = (unsigned short*)alloc(16384ull * 216 * 2);  // bf16
  unsigned short* dcnt  = (unsigned short*)alloc(16384ull * 256 * 2);
  unsigned short* d1t   = (unsigned short*)alloc(16384ull * 256 * 2);  // 8 MB
  unsigned short* p1t   = (unsigned short*)alloc(16384ull * 768 * 2);  // 24 MB
  // conv1 split-K bf16 partials (16 MB) alias d1t+p1t (dead until S2/pw1):
  unsigned short* part = d1t;
  unsigned short* wc1   = (unsigned short*)alloc(128ull * 2304 * 2);
  unsigned short* wc2   = (unsigned short*)alloc(256ull * 1152 * 2);
  // wval and wom MUST be contiguous (fused val/om B-matrix, 472 x 256):
  unsigned short* wval  = (unsigned short*)alloc(256ull * 256 * 2);   // 256-mult
  unsigned short* wom   = (unsigned short*)alloc(216ull * 256 * 2);   // = wval + 65536
  unsigned short* woutp = (unsigned short*)alloc(256ull * 256 * 2);
  unsigned short* wpw1  = (unsigned short*)alloc(768ull * 256 * 2);
  unsigned short* wpw2  = (unsigned short*)alloc(256ull * 768 * 2);
  unsigned short* zpage = (unsigned short*)alloc(256);  // 64B zeros (+pad)

  // prep: tokens + weight conversions
  prep_k<<<3544, 256, 0, stream>>>(x, xt, cv1_w, wc1, cv2_w, wc2, val_w, wval,
                                   om_w, wom, outp_w, woutp, pw1_w, wpw1,
                                   pw2_w, wpw2, (uint32*)zpage);

  // S1: conv1 split-K4 -> bf16 partials ∪ val/om projection (om bf16)
  fused_s1<<<1024, 256, 0, stream>>>(xt, wc1, part, wval, val_b, om_b, omf,
                                     valt, zpage);

  // R: y1 reduce+BN+SiLU ∪ dcn core (us8, 8 pix/block)
  fused_r<<<3072, 256, 0, stream>>>(part, cv1_g, cv1_b, cv1_m, cv1_v, y1t,
                                    valt, omf, dcnt);

  // S2: conv2 (BK=64) ∪ outp (BK=64)
  fused_s2<<<1024, 256, 0, stream>>>(y1t, wc2, cv2_g, cv2_b, cv2_m, cv2_v, y2t,
                                     dcnt, woutp, outp_b, bn3_g, bn3_b, bn3_m,
                                     bn3_v, d1t, zpage);

  // pw1 (768 blocks, BK=32 BN=128), pw2 + residual (512 blocks, BK=64)
  gemm_k<4, 0, 128><<<dim3(6, 128), 256, 0, stream>>>(
      d1t, wpw1, pw1_b, 256, 768, p1t, nullptr, nullptr, nullptr, nullptr, zpage);
  gemm_k64<6><<<dim3(4, 128), 256, 0, stream>>>(
      p1t, wpw2, pw2_b, 768, 256, out, x, (const float*)y2t, nullptr, nullptr, zpage);
}

// Round 17
// 152.875 us; speedup vs baseline: 1.1097x; 1.0207x over previous
//
#include <hip/hip_runtime.h>
#include <math.h>

typedef __attribute__((ext_vector_type(8))) __bf16 bf16x8;
typedef __attribute__((ext_vector_type(8))) unsigned short us8;
typedef __attribute__((ext_vector_type(4))) unsigned short us4;
typedef __attribute__((ext_vector_type(4))) float f32x4;
typedef __attribute__((ext_vector_type(4))) int i32x4;
typedef unsigned int uint32;

#define EPSV 1e-5f

__device__ __forceinline__ float silu_f(float v) { return v / (1.f + __expf(-v)); }

__device__ __forceinline__ unsigned short f2bf(float f) {
  uint32 u = __builtin_bit_cast(uint32, f);
  u += 0x7fffu + ((u >> 16) & 1u);   // RNE
  return (unsigned short)(u >> 16);
}
__device__ __forceinline__ float bf2f(unsigned short h) {
  uint32 u = ((uint32)h) << 16;
  return __builtin_bit_cast(float, u);
}

// async global->LDS DMA, 16B per lane. LDS dest = wave-uniform base + lane*16.
__device__ __forceinline__ void gl_lds16(const void* g, void* l) {
  __builtin_amdgcn_global_load_lds(
      (const __attribute__((address_space(1))) unsigned int*)g,
      (__attribute__((address_space(3))) unsigned int*)l, 16, 0, 0);
}

// ---------------------------------------------------------------------------
// GEMM body (BK=32).  BM=128; BN in {128, 64}.  4 waves.  R12/R14-proven.
// EPI: 2 BN+SiLU->bf16 | 3 bias+BN->bf16 | 4 bias+SiLU->bf16
//      5 split val/om (om -> bf16) | 6 bias+x+y2 -> NCHW f32 | 7 raw bf16
// ---------------------------------------------------------------------------
template <int EPI, int CIN, int BN>
__device__ __forceinline__ void gemm_body(
    int rb, int cb, int k0, int KL,
    const unsigned short* __restrict__ A, const unsigned short* __restrict__ Bw,
    const float* __restrict__ bias, int K, int Co, void* __restrict__ outv,
    const float* __restrict__ e0, const float* __restrict__ e1,
    const float* __restrict__ e2, const float* __restrict__ e3,
    const unsigned short* __restrict__ zpage, bf16x8* smem) {
  constexpr int NFR = BN / 32;
  constexpr int NB = BN / 64;
  constexpr int CPB = 512 + BN * 4;
  const int t = threadIdx.x;
  const int lane = t & 63;
  const int wv = t >> 6;
  const int wr = wv >> 1, wc = wv & 1;

  f32x4 acc[4][NFR];
#pragma unroll
  for (int i = 0; i < 4; i++)
#pragma unroll
    for (int j = 0; j < NFR; j++) acc[i][j] = (f32x4){0.f, 0.f, 0.f, 0.f};

  const unsigned short* Abase[2];
  int aprow[2], apcol[2], akoff[2];
#pragma unroll
  for (int i = 0; i < 2; i++) {
    int c = t + 256 * i;
    int row = (c >> 6) * 16 + (c & 15);
    int koff = ((c >> 4) & 3) * 8;
    akoff[i] = koff;
    int grow = rb + row;
    if constexpr (CIN > 0) {
      int n = grow >> 12, p = grow & 4095;
      aprow[i] = p >> 6;
      apcol[i] = p & 63;
      Abase[i] = A + (size_t)n * 4096 * CIN;
    } else {
      Abase[i] = A + (size_t)grow * K + koff;
    }
  }
  const unsigned short* Bbase[NB];
#pragma unroll
  for (int i = 0; i < NB; i++) {
    int c = t + 256 * i;
    int col = cb + (c >> 6) * 16 + (c & 15);
    int koff = ((c >> 4) & 3) * 8;
    Bbase[i] = (col < Co) ? (Bw + (size_t)col * K + koff) : zpage;
  }
  auto addrA = [&](int i, int kb) -> const unsigned short* {
    if constexpr (CIN > 0) {
      int tap = kb / CIN;
      int ci = (kb & (CIN - 1)) + akoff[i];
      int dy = tap / 3 - 1, dx = tap % 3 - 1;
      int h = aprow[i] + dy, w = apcol[i] + dx;
      if (((unsigned)h < 64u) & ((unsigned)w < 64u))
        return &Abase[i][(size_t)(h * 64 + w) * CIN + ci];
      return zpage;
    } else {
      return Abase[i] + kb;
    }
  };
  auto stage = [&](int buf, int kb) {
    bf16x8* base = &smem[buf * CPB];
    gl_lds16(addrA(0, kb), (void*)&base[t]);
    gl_lds16(addrA(1, kb), (void*)&base[t + 256]);
    gl_lds16((Bbase[0] == zpage) ? zpage : Bbase[0] + kb, (void*)&base[512 + t]);
    if constexpr (NB == 2)
      gl_lds16((Bbase[1] == zpage) ? zpage : Bbase[1] + kb,
               (void*)&base[512 + t + 256]);
  };

  const int nt = KL >> 5;
  stage(0, k0);
  __syncthreads();
  int cur = 0;
  for (int it = 0; it < nt; ++it) {
    if (it + 1 < nt) stage(cur ^ 1, k0 + ((it + 1) << 5));
    const bf16x8* Ab = &smem[cur * CPB];
    const bf16x8* Bb = Ab + 512;
    bf16x8 af[4], bfr[NFR];
#pragma unroll
    for (int mi = 0; mi < 4; mi++) af[mi] = Ab[(wr * 4 + mi) * 64 + lane];
#pragma unroll
    for (int ni = 0; ni < NFR; ni++) bfr[ni] = Bb[(wc * NFR + ni) * 64 + lane];
    __builtin_amdgcn_s_setprio(1);
#pragma unroll
    for (int mi = 0; mi < 4; mi++)
#pragma unroll
      for (int ni = 0; ni < NFR; ni++)
        acc[mi][ni] = __builtin_amdgcn_mfma_f32_16x16x32_bf16(af[mi], bfr[ni],
                                                              acc[mi][ni], 0, 0, 0);
    __builtin_amdgcn_s_setprio(0);
    __syncthreads();
    cur ^= 1;
  }

  // ---- epilogue.  C/D: col = lane&15, row = (lane>>4)*4 + reg
  const int lr = lane & 15, kg4 = (lane >> 4) * 4;
#pragma unroll
  for (int mi = 0; mi < 4; mi++) {
#pragma unroll
    for (int ni = 0; ni < NFR; ni++) {
      int gcol = cb + wc * (BN / 2) + ni * 16 + lr;
      if (gcol >= Co) continue;
      float bval, s = 1.f, tt = 0.f;
      if (EPI == 2 || EPI == 7) bval = 0.f;
      else if (EPI == 5) bval = (gcol < 256) ? bias[gcol] : e0[gcol - 256];
      else bval = bias[gcol];
      if (EPI == 2 || EPI == 3) {
        s = e0[gcol] * rsqrtf(e3[gcol] + EPSV);
        tt = e1[gcol] - e2[gcol] * s;
      }
      if (EPI == 6) {
        int grow0 = rb + wr * 64 + mi * 16 + kg4;
        int n = grow0 >> 12, p0 = grow0 & 4095;
        size_t oix = ((size_t)(n * 256 + gcol)) * 4096 + p0;
        f32x4 xv = *(const f32x4*)&((const float*)e0)[oix];
        const unsigned short* y2p = (const unsigned short*)e1;
        f32x4 ov;
#pragma unroll
        for (int j = 0; j < 4; j++) {
          float y2 = bf2f(y2p[((size_t)(n * 4096 + p0 + j)) * 256 + gcol]);
          ov[j] = acc[mi][ni][j] + bval + xv[j] + y2;
        }
        *(f32x4*)&((float*)outv)[oix] = ov;
        continue;
      }
#pragma unroll
      for (int j = 0; j < 4; j++) {
        int grow = rb + wr * 64 + mi * 16 + kg4 + j;
        float v = acc[mi][ni][j] + bval;
        if (EPI == 2) v = silu_f(v * s + tt);
        if (EPI == 3) v = v * s + tt;
        if (EPI == 4) v = silu_f(v);
        if (EPI == 5) {
          if (gcol < 256)
            ((unsigned short*)outv)[(size_t)grow * 256 + gcol] = f2bf(v);
          else
            ((unsigned short*)e1)[(size_t)grow * 216 + (gcol - 256)] = f2bf(v);
        } else {
          ((unsigned short*)outv)[(size_t)grow * Co + gcol] = f2bf(v);
        }
      }
    }
  }
}

// ---------------------------------------------------------------------------
// GEMM body BK=64, BN=64, BM=128.  4 waves, 64x32 out each, 16 MFMA/iter.
// LDS 24KB/buf, dbuf 48KB.  R14-proven (conv2/outp/pw2 shapes).
// EPI: 2 BN+SiLU->bf16 | 3 bias+BN->bf16 | 6 bias+x+y2 -> NCHW f32
// ---------------------------------------------------------------------------
template <int EPI, int CIN>
__device__ __forceinline__ void gemm_body64(
    int rb, int cb, int k0, int KL,
    const unsigned short* __restrict__ A, const unsigned short* __restrict__ Bw,
    const float* __restrict__ bias, int K, int Co, void* __restrict__ outv,
    const float* __restrict__ e0, const float* __restrict__ e1,
    const float* __restrict__ e2, const float* __restrict__ e3,
    const unsigned short* __restrict__ zpage, bf16x8* smem) {
  constexpr int CPB = 1536;
  const int t = threadIdx.x;
  const int lane = t & 63;
  const int wv = t >> 6;
  const int wr = wv >> 1, wc = wv & 1;

  f32x4 acc[4][2];
#pragma unroll
  for (int i = 0; i < 4; i++)
#pragma unroll
    for (int j = 0; j < 2; j++) acc[i][j] = (f32x4){0.f, 0.f, 0.f, 0.f};

  const unsigned short* Abase[4];
  int aprow[4], apcol[4], akoff[4];
#pragma unroll
  for (int i = 0; i < 4; i++) {
    int c = t + 256 * i;
    int row = (c >> 7) * 16 + (c & 15);
    int koff = ((c >> 6) & 1) * 32 + ((c >> 4) & 3) * 8;
    akoff[i] = koff;
    int grow = rb + row;
    if constexpr (CIN > 0) {
      int n = grow >> 12, p = grow & 4095;
      aprow[i] = p >> 6;
      apcol[i] = p & 63;
      Abase[i] = A + (size_t)n * 4096 * CIN;
    } else {
      Abase[i] = A + (size_t)grow * K + koff;
    }
  }
  const unsigned short* Bbase[2];
#pragma unroll
  for (int i = 0; i < 2; i++) {
    int c = t + 256 * i;
    int col = cb + (c >> 7) * 16 + (c & 15);
    int koff = ((c >> 6) & 1) * 32 + ((c >> 4) & 3) * 8;
    Bbase[i] = (col < Co) ? (Bw + (size_t)col * K + koff) : zpage;
  }
  auto addrA = [&](int i, int kb) -> const unsigned short* {
    if constexpr (CIN > 0) {
      int tap = kb / CIN;
      int ci = (kb & (CIN - 1)) + akoff[i];
      int dy = tap / 3 - 1, dx = tap % 3 - 1;
      int h = aprow[i] + dy, w = apcol[i] + dx;
      if (((unsigned)h < 64u) & ((unsigned)w < 64u))
        return &Abase[i][(size_t)(h * 64 + w) * CIN + ci];
      return zpage;
    } else {
      return Abase[i] + kb;
    }
  };
  auto stage = [&](int buf, int kb) {
    bf16x8* base = &smem[buf * CPB];
#pragma unroll
    for (int i = 0; i < 4; i++)
      gl_lds16(addrA(i, kb), (void*)&base[t + 256 * i]);
    gl_lds16((Bbase[0] == zpage) ? zpage : Bbase[0] + kb,
             (void*)&base[1024 + t]);
    gl_lds16((Bbase[1] == zpage) ? zpage : Bbase[1] + kb,
             (void*)&base[1024 + t + 256]);
  };

  const int nt = KL >> 6;
  stage(0, k0);
  __syncthreads();
  int cur = 0;
  for (int it = 0; it < nt; ++it) {
    if (it + 1 < nt) stage(cur ^ 1, k0 + ((it + 1) << 6));
    const bf16x8* Ab = &smem[cur * CPB];
    const bf16x8* Bb = Ab + 1024;
    __builtin_amdgcn_s_setprio(1);
#pragma unroll
    for (int ks = 0; ks < 2; ks++) {
      bf16x8 af[4], bfr[2];
#pragma unroll
      for (int mi = 0; mi < 4; mi++)
        af[mi] = Ab[((wr * 4 + mi) * 2 + ks) * 64 + lane];
#pragma unroll
      for (int ni = 0; ni < 2; ni++)
        bfr[ni] = Bb[((wc * 2 + ni) * 2 + ks) * 64 + lane];
#pragma unroll
      for (int mi = 0; mi < 4; mi++)
#pragma unroll
        for (int ni = 0; ni < 2; ni++)
          acc[mi][ni] = __builtin_amdgcn_mfma_f32_16x16x32_bf16(
              af[mi], bfr[ni], acc[mi][ni], 0, 0, 0);
    }
    __builtin_amdgcn_s_setprio(0);
    __syncthreads();
    cur ^= 1;
  }

  const int lr = lane & 15, kg4 = (lane >> 4) * 4;
#pragma unroll
  for (int mi = 0; mi < 4; mi++) {
#pragma unroll
    for (int ni = 0; ni < 2; ni++) {
      int gcol = cb + wc * 32 + ni * 16 + lr;
      if (gcol >= Co) continue;
      float bval, s = 1.f, tt = 0.f;
      if (EPI == 2) bval = 0.f;
      else bval = bias[gcol];
      if (EPI == 2 || EPI == 3) {
        s = e0[gcol] * rsqrtf(e3[gcol] + EPSV);
        tt = e1[gcol] - e2[gcol] * s;
      }
      if (EPI == 6) {
        int grow0 = rb + wr * 64 + mi * 16 + kg4;
        int n = grow0 >> 12, p0 = grow0 & 4095;
        size_t oix = ((size_t)(n * 256 + gcol)) * 4096 + p0;
        f32x4 xv = *(const f32x4*)&((const float*)e0)[oix];
        const unsigned short* y2p = (const unsigned short*)e1;
        f32x4 ov;
#pragma unroll
        for (int j = 0; j < 4; j++) {
          float y2 = bf2f(y2p[((size_t)(n * 4096 + p0 + j)) * 256 + gcol]);
          ov[j] = acc[mi][ni][j] + bval + xv[j] + y2;
        }
        *(f32x4*)&((float*)outv)[oix] = ov;
        continue;
      }
#pragma unroll
      for (int j = 0; j < 4; j++) {
        int grow = rb + wr * 64 + mi * 16 + kg4 + j;
        float v = acc[mi][ni][j] + bval;
        if (EPI == 2) v = silu_f(v * s + tt);
        if (EPI == 3) v = v * s + tt;
        ((unsigned short*)outv)[(size_t)grow * Co + gcol] = f2bf(v);
      }
    }
  }
}

// ---------------------------------------------------------------------------
// DCNv4 core body v3: 8 pixels/block, lanes carry 8 channels; om bf16.
// ---------------------------------------------------------------------------
__device__ __forceinline__ void dcn_body(
    int bid, const unsigned short* __restrict__ value,
    const unsigned short* __restrict__ om, unsigned short* __restrict__ out,
    void* smemraw) {
  f32x4* wgt = (f32x4*)smemraw;
  i32x4* adr = (i32x4*)((char*)smemraw + 576 * 16);
  const int n = bid >> 9;
  const int p0 = (bid & 511) * 8;
  const int t = threadIdx.x;

  for (int idx = t; idx < 576; idx += 256) {
    int pi = idx / 72;
    int gk = idx - pi * 72;
    int g = gk / 9, k = gk - g * 9;
    int p = p0 + pi;
    int h0 = p >> 6, w0 = p & 63;
    const unsigned short* omp = om + ((size_t)(n * 4096 + p)) * 216 + g * 27;
    float ox = bf2f(omp[2 * k]), oy = bf2f(omp[2 * k + 1]);
    float mk = bf2f(omp[18 + k]);
    float px = (float)(w0 + (k % 3) - 1) + ox;
    float py = (float)(h0 + (k / 3) - 1) + oy;
    float x0f = floorf(px), y0f = floorf(py);
    float lx = px - x0f, ly = py - y0f;
    int x0 = (int)x0f, y0 = (int)y0f;
    int x1 = x0 + 1, y1 = y0 + 1;
    bool vx0 = (unsigned)x0 < 64u, vx1 = (unsigned)x1 < 64u;
    bool vy0 = (unsigned)y0 < 64u, vy1 = (unsigned)y1 < 64u;
    int cx0 = min(max(x0, 0), 63), cx1 = min(max(x1, 0), 63);
    int cy0 = min(max(y0, 0), 63), cy1 = min(max(y1, 0), 63);
    f32x4 w4;
    w4[0] = (1.f - ly) * (1.f - lx) * mk * (float)(vy0 && vx0);
    w4[1] = (1.f - ly) * lx * mk * (float)(vy0 && vx1);
    w4[2] = ly * (1.f - lx) * mk * (float)(vy1 && vx0);
    w4[3] = ly * lx * mk * (float)(vy1 && vx1);
    i32x4 a4;
    a4[0] = (cy0 * 64 + cx0) * 256;
    a4[1] = (cy0 * 64 + cx1) * 256;
    a4[2] = (cy1 * 64 + cx0) * 256;
    a4[3] = (cy1 * 64 + cx1) * 256;
    wgt[idx] = w4;
    adr[idx] = a4;
  }
  __syncthreads();

  const int pi = t >> 5;
  const int g = (t >> 2) & 7;
  const int l = t & 3;
  const int p = p0 + pi;
  const unsigned short* vb = value + ((size_t)n * 4096) * 256 + g * 32 + l * 8;
  const int bix = (pi * 8 + g) * 9;
  float a[8] = {0.f, 0.f, 0.f, 0.f, 0.f, 0.f, 0.f, 0.f};
#pragma unroll
  for (int k = 0; k < 9; k++) {
    f32x4 wv = wgt[bix + k];
    i32x4 av = adr[bix + k];
    us8 q0 = *(const us8*)(vb + av[0]);
    us8 q1 = *(const us8*)(vb + av[1]);
    us8 q2 = *(const us8*)(vb + av[2]);
    us8 q3 = *(const us8*)(vb + av[3]);
#pragma unroll
    for (int j = 0; j < 8; j++)
      a[j] += wv[0] * bf2f(q0[j]) + wv[1] * bf2f(q1[j]) +
              wv[2] * bf2f(q2[j]) + wv[3] * bf2f(q3[j]);
  }
  us8 o;
#pragma unroll
  for (int j = 0; j < 8; j++) o[j] = f2bf(a[j]);
  *(us8*)&out[((size_t)(n * 4096 + p)) * 256 + g * 32 + l * 8] = o;
}

// ---------------------------------------------------------------------------
// PREP (1624 blocks): xt transpose (0..1023) + wc1 cvt (1024..1151) +
// wval/wom cvt (1152..1623).  Late-consumed weights moved to S1 filler.
// ---------------------------------------------------------------------------
__global__ __launch_bounds__(256) void prep_k(
    const float* __restrict__ x, unsigned short* __restrict__ xt,
    const float* __restrict__ c1, unsigned short* __restrict__ o1,
    const float* __restrict__ a0, unsigned short* __restrict__ b0,
    const float* __restrict__ a1, unsigned short* __restrict__ b1,
    uint32* __restrict__ zp) {
  __shared__ float lds[64][65];
  int b = blockIdx.x;
  const int t = threadIdx.x;
  if (b == 0 && t < 32) zp[t] = 0u;
  if (b < 1024) {
    const int p0 = (b & 63) * 64, c0 = ((b >> 6) & 3) * 64, n = b >> 8;
    const int pp = t & 63, ccb = t >> 6;
    const float* xb = x + ((size_t)n * 256 + c0) * 4096 + p0;
#pragma unroll
    for (int i = 0; i < 16; i++) {
      int cc = ccb * 16 + i;
      lds[pp][cc] = xb[(size_t)cc * 4096 + pp];
    }
    __syncthreads();
#pragma unroll
    for (int i = 0; i < 2; i++) {
      int pp2 = (t >> 3) + i * 32;
      int c8 = (t & 7) * 8;
      us8 v;
#pragma unroll
      for (int j = 0; j < 8; j++) v[j] = f2bf(lds[pp2][c8 + j]);
      *(us8*)&xt[((size_t)(n * 4096 + p0 + pp2)) * 256 + c0 + c8] = v;
    }
    return;
  }
  if (b < 1152) {  // conv1 weights: thread per (co,ci), 9 contiguous taps
    int idx = (b - 1024) * 256 + t;
    int co = idx >> 8, ci = idx & 255;
    const float* src = c1 + (size_t)(co * 256 + ci) * 9;
#pragma unroll
    for (int tap = 0; tap < 9; tap++)
      o1[(size_t)(co * 9 + tap) * 256 + ci] = f2bf(src[tap]);
    return;
  }
  int idx = (b - 1152) * 256 + t;   // 0..120831: wval then wom
  if (idx < 65536) b0[idx] = f2bf(a0[idx]);
  else if (idx < 120832) b1[idx - 65536] = f2bf(a1[idx - 65536]);
}

// ---------------------------------------------------------------------------
// S1 (1600 blocks): 0..511 conv1 split-K x4 (bf16 partials, BK=32 BN=128),
// 512..1023 val/om projection (BK=32 BN=128), 1024..1471 plain weight cvts
// (woutp/wpw1/wpw2, 4 elems/thread), 1472..1599 wc2 cvt.
// ---------------------------------------------------------------------------
__global__ __launch_bounds__(256) void fused_s1(
    const unsigned short* __restrict__ xt,
    const unsigned short* __restrict__ wc1, unsigned short* __restrict__ part,
    const unsigned short* __restrict__ wval, const float* __restrict__ val_b,
    const float* __restrict__ om_b, unsigned short* __restrict__ omf,
    unsigned short* __restrict__ valt, const unsigned short* __restrict__ zpage,
    const float* __restrict__ outp_w, unsigned short* __restrict__ woutp,
    const float* __restrict__ pw1_w, unsigned short* __restrict__ wpw1,
    const float* __restrict__ pw2_w, unsigned short* __restrict__ wpw2,
    const float* __restrict__ cv2_w, unsigned short* __restrict__ wc2) {
  __shared__ bf16x8 smem[2048];
  int b = blockIdx.x;
  const int t = threadIdx.x;
  if (b < 512) {
    int s = b >> 7, mt = b & 127;
    gemm_body<7, 256, 128>(mt * 128, 0, s * 576, 576, xt, wc1, nullptr, 2304,
                           128, part + (size_t)s * 2097152, nullptr, nullptr,
                           nullptr, nullptr, zpage, smem);
  } else if (b < 1024) {
    int v = b - 512;
    gemm_body<5, 0, 128>((v >> 2) * 128, (v & 3) * 128, 0, 256, xt, wval, val_b,
                         256, 472, valt, om_b, (const float*)(const void*)omf,
                         nullptr, nullptr, zpage, smem);
  } else if (b < 1472) {
    int idx4 = (b - 1024) * 1024 + t * 4;   // 458752 elems total
    const float* s;
    unsigned short* d;
    int off;
    if (idx4 < 65536)       { s = outp_w; d = woutp; off = idx4; }
    else if (idx4 < 262144) { s = pw1_w;  d = wpw1;  off = idx4 - 65536; }
    else                    { s = pw2_w;  d = wpw2;  off = idx4 - 262144; }
    f32x4 v = *(const f32x4*)&s[off];
    us4 o;
#pragma unroll
    for (int j = 0; j < 4; j++) o[j] = f2bf(v[j]);
    *(us4*)&d[off] = o;
  } else {
    int idx = (b - 1472) * 256 + t;   // 32768 (co,ci) pairs
    int co = idx >> 7, ci = idx & 127;
    const float* src = cv2_w + (size_t)(co * 128 + ci) * 9;
#pragma unroll
    for (int tap = 0; tap < 9; tap++)
      wc2[(size_t)(co * 9 + tap) * 128 + ci] = f2bf(src[tap]);
  }
}

// ---------------------------------------------------------------------------
// R (3072 blocks): 0..1023 y1 reduce+BN+SiLU, 1024..3071 dcn v3.
// ---------------------------------------------------------------------------
__global__ __launch_bounds__(256) void fused_r(
    const unsigned short* __restrict__ part, const float* __restrict__ g1,
    const float* __restrict__ bb1, const float* __restrict__ m1,
    const float* __restrict__ v1, unsigned short* __restrict__ y1t,
    const unsigned short* __restrict__ valt, const unsigned short* __restrict__ omf,
    unsigned short* __restrict__ dcnt) {
  __shared__ char rsm[18432];
  int b = blockIdx.x;
  if (b < 1024) {
    int g = b * 256 + threadIdx.x;
    int grow = g >> 4;
    int co8 = (g & 15) << 3;
    size_t base = (size_t)grow * 128 + co8;
    float sum[8] = {0.f, 0.f, 0.f, 0.f, 0.f, 0.f, 0.f, 0.f};
#pragma unroll
    for (int s = 0; s < 4; s++) {
      us8 pv = *(const us8*)&part[base + (size_t)s * 2097152];
#pragma unroll
      for (int j = 0; j < 8; j++) sum[j] += bf2f(pv[j]);
    }
    us8 o;
#pragma unroll
    for (int j = 0; j < 8; j++) {
      int co = co8 + j;
      float sc = g1[co] * rsqrtf(v1[co] + EPSV);
      float tt = bb1[co] - m1[co] * sc;
      o[j] = f2bf(silu_f(sum[j] * sc + tt));
    }
    *(us8*)&y1t[base] = o;
  } else {
    dcn_body(b - 1024, valt, omf, dcnt, (void*)rsm);
  }
}

// ---------------------------------------------------------------------------
// S2 (512 blocks, BK=64): outp only (bias+BN3 -> d1t).
// ---------------------------------------------------------------------------
__global__ __launch_bounds__(256) void s2_outp(
    const unsigned short* __restrict__ dcnt, const unsigned short* __restrict__ woutp,
    const float* __restrict__ outp_b, const float* __restrict__ g3,
    const float* __restrict__ bb3, const float* __restrict__ m3,
    const float* __restrict__ v3, unsigned short* __restrict__ d1t,
    const unsigned short* __restrict__ zpage) {
  __shared__ bf16x8 smem[3072];
  int b = blockIdx.x;
  gemm_body64<3, 0>((b >> 2) * 128, (b & 3) * 64, 0, 256, dcnt, woutp,
                    outp_b, 256, 256, d1t, g3, bb3, m3, v3, zpage, smem);
}

// ---------------------------------------------------------------------------
// P (1280 blocks): 0..511 conv2 (BK=64, BN+SiLU -> y2t), 512..1279 pw1
// (BK=32 BN=128, bias+SiLU -> p1t).
// ---------------------------------------------------------------------------
__global__ __launch_bounds__(256) void fused_p(
    const unsigned short* __restrict__ y1t,
    const unsigned short* __restrict__ wc2, const float* __restrict__ g2,
    const float* __restrict__ bb2, const float* __restrict__ m2,
    const float* __restrict__ v2, unsigned short* __restrict__ y2t,
    const unsigned short* __restrict__ d1t, const unsigned short* __restrict__ wpw1,
    const float* __restrict__ pw1_b, unsigned short* __restrict__ p1t,
    const unsigned short* __restrict__ zpage) {
  __shared__ bf16x8 smem[3072];   // 48 KB (conv2 uses all; pw1 uses 32 KB)
  int b = blockIdx.x;
  if (b < 512) {
    gemm_body64<2, 128>((b >> 2) * 128, (b & 3) * 64, 0, 1152, y1t, wc2,
                        nullptr, 1152, 256, y2t, g2, bb2, m2, v2, zpage, smem);
  } else {
    int q = b - 512;
    gemm_body<4, 0, 128>((q / 6) * 128, (q % 6) * 128, 0, 256, d1t, wpw1,
                         pw1_b, 256, 768, p1t, nullptr, nullptr, nullptr,
                         nullptr, zpage, smem);
  }
}

// ---------------------------------------------------------------------------
// pw2 + residual (512 blocks, BK=64, EPI 6).
// ---------------------------------------------------------------------------
__global__ __launch_bounds__(256) void pw2_k(
    const unsigned short* __restrict__ p1t, const unsigned short* __restrict__ wpw2,
    const float* __restrict__ pw2_b, const float* __restrict__ x,
    const unsigned short* __restrict__ y2t, float* __restrict__ out,
    const unsigned short* __restrict__ zpage) {
  __shared__ bf16x8 smem[3072];
  int b = blockIdx.x;
  gemm_body64<6, 0>((b >> 2) * 128, (b & 3) * 64, 0, 768, p1t, wpw2, pw2_b,
                    768, 256, out, x, (const float*)(const void*)y2t,
                    nullptr, nullptr, zpage, smem);
}

// ---------------------------------------------------------------------------
extern "C" void kernel_launch(void* const* d_in, const int* in_sizes, int n_in,
                              void* d_out, int out_size, void* d_ws,
                              size_t ws_size, hipStream_t stream) {
  const float* x      = (const float*)d_in[0];
  const float* cv1_w  = (const float*)d_in[1];
  const float* cv1_g  = (const float*)d_in[2];
  const float* cv1_b  = (const float*)d_in[3];
  const float* cv1_m  = (const float*)d_in[4];
  const float* cv1_v  = (const float*)d_in[5];
  const float* cv2_w  = (const float*)d_in[6];
  const float* cv2_g  = (const float*)d_in[7];
  const float* cv2_b  = (const float*)d_in[8];
  const float* cv2_m  = (const float*)d_in[9];
  const float* cv2_v  = (const float*)d_in[10];
  const float* val_w  = (const float*)d_in[11];
  const float* val_b  = (const float*)d_in[12];
  const float* om_w   = (const float*)d_in[13];
  const float* om_b   = (const float*)d_in[14];
  const float* outp_w = (const float*)d_in[15];
  const float* outp_b = (const float*)d_in[16];
  const float* bn3_g  = (const float*)d_in[17];
  const float* bn3_b  = (const float*)d_in[18];
  const float* bn3_m  = (const float*)d_in[19];
  const float* bn3_v  = (const float*)d_in[20];
  const float* pw1_w  = (const float*)d_in[21];
  const float* pw1_b  = (const float*)d_in[22];
  const float* pw2_w  = (const float*)d_in[23];
  const float* pw2_b  = (const float*)d_in[24];
  float* out = (float*)d_out;

  char* w = (char*)d_ws;
  auto alloc = [&](size_t bytes) {
    char* p = w;
    w += (bytes + 255) & ~(size_t)255;
    return p;
  };
  unsigned short* xt    = (unsigned short*)alloc(16384ull * 256 * 2);
  unsigned short* y1t   = (unsigned short*)alloc(16384ull * 128 * 2);
  unsigned short* y2t   = (unsigned short*)alloc(16384ull * 256 * 2);
  unsigned short* valt  = (unsigned short*)alloc(16384ull * 256 * 2);
  unsigned short* omf   = (unsigned short*)alloc(16384ull * 216 * 2);  // bf16
  unsigned short* dcnt  = (unsigned short*)alloc(16384ull * 256 * 2);
  unsigned short* d1t   = (unsigned short*)alloc(16384ull * 256 * 2);  // 8 MB
  unsigned short* p1t   = (unsigned short*)alloc(16384ull * 768 * 2);  // 24 MB
  // conv1 split-K bf16 partials (16 MB) alias d1t+p1t (dead until S2/P):
  unsigned short* part = d1t;
  unsigned short* wc1   = (unsigned short*)alloc(128ull * 2304 * 2);
  unsigned short* wc2   = (unsigned short*)alloc(256ull * 1152 * 2);
  // wval and wom MUST be contiguous (fused val/om B-matrix, 472 x 256):
  unsigned short* wval  = (unsigned short*)alloc(256ull * 256 * 2);   // 256-mult
  unsigned short* wom   = (unsigned short*)alloc(216ull * 256 * 2);   // = wval + 65536
  unsigned short* woutp = (unsigned short*)alloc(256ull * 256 * 2);
  unsigned short* wpw1  = (unsigned short*)alloc(768ull * 256 * 2);
  unsigned short* wpw2  = (unsigned short*)alloc(256ull * 768 * 2);
  unsigned short* zpage = (unsigned short*)alloc(256);  // 64B zeros (+pad)

  // prep: xt + early weights (wc1, wval/wom)
  prep_k<<<1624, 256, 0, stream>>>(x, xt, cv1_w, wc1, val_w, wval, om_w, wom,
                                   (uint32*)zpage);

  // S1: conv1 split-K4 ∪ val/om ∪ late-weight cvts (filler)
  fused_s1<<<1600, 256, 0, stream>>>(xt, wc1, part, wval, val_b, om_b, omf,
                                     valt, zpage, outp_w, woutp, pw1_w, wpw1,
                                     pw2_w, wpw2, cv2_w, wc2);

  // R: y1 reduce+BN+SiLU ∪ dcn core
  fused_r<<<3072, 256, 0, stream>>>(part, cv1_g, cv1_b, cv1_m, cv1_v, y1t,
                                    valt, omf, dcnt);

  // S2: outp only (fast)
  s2_outp<<<512, 256, 0, stream>>>(dcnt, woutp, outp_b, bn3_g, bn3_b, bn3_m,
                                   bn3_v, d1t, zpage);

  // P: conv2 ∪ pw1
  fused_p<<<1280, 256, 0, stream>>>(y1t, wc2, cv2_g, cv2_b, cv2_m, cv2_v, y2t,
                                    d1t, wpw1, pw1_b, p1t, zpage);

  // pw2 + residual
  pw2_k<<<512, 256, 0, stream>>>(p1t, wpw2, pw2_b, x, y2t, out, zpage);
}

// Round 19
// 147.809 us; speedup vs baseline: 1.1478x; 1.0343x over previous
//
#include <hip/hip_runtime.h>
#include <math.h>

typedef __attribute__((ext_vector_type(8))) __bf16 bf16x8;
typedef __attribute__((ext_vector_type(8))) unsigned short us8;
typedef __attribute__((ext_vector_type(4))) unsigned short us4;
typedef __attribute__((ext_vector_type(4))) float f32x4;
typedef __attribute__((ext_vector_type(4))) int i32x4;
typedef unsigned int uint32;

#define EPSV 1e-5f

__device__ __forceinline__ float silu_f(float v) { return v / (1.f + __expf(-v)); }

__device__ __forceinline__ unsigned short f2bf(float f) {
  uint32 u = __builtin_bit_cast(uint32, f);
  u += 0x7fffu + ((u >> 16) & 1u);   // RNE
  return (unsigned short)(u >> 16);
}
__device__ __forceinline__ float bf2f(unsigned short h) {
  uint32 u = ((uint32)h) << 16;
  return __builtin_bit_cast(float, u);
}

// Within-range XCD swizzle (n % 8 == 0, bijective): HW maps block i -> XCD
// i%8, so this gives each XCD a CONTIGUOUS run of logical tiles (L2 reuse of
// im2col halos / shared A-slabs).  Applied per homogeneous sub-range only —
// never across different sub-kernels (R10 lesson).
__device__ __forceinline__ int xsr(int i, int n) {
  return (i & 7) * (n >> 3) + (i >> 3);
}

// async global->LDS DMA, 16B per lane. LDS dest = wave-uniform base + lane*16.
__device__ __forceinline__ void gl_lds16(const void* g, void* l) {
  __builtin_amdgcn_global_load_lds(
      (const __attribute__((address_space(1))) unsigned int*)g,
      (__attribute__((address_space(3))) unsigned int*)l, 16, 0, 0);
}

// ---------------------------------------------------------------------------
// GEMM body (BK=32).  BM=128; BN in {128, 64}.  4 waves.  R12/R14-proven.
// EPI: 2 BN+SiLU->bf16 | 3 bias+BN->bf16 | 4 bias+SiLU->bf16
//      5 split val/om (om -> bf16) | 6 bias+x+y2 -> NCHW f32 | 7 raw bf16
// ---------------------------------------------------------------------------
template <int EPI, int CIN, int BN>
__device__ __forceinline__ void gemm_body(
    int rb, int cb, int k0, int KL,
    const unsigned short* __restrict__ A, const unsigned short* __restrict__ Bw,
    const float* __restrict__ bias, int K, int Co, void* __restrict__ outv,
    const float* __restrict__ e0, const float* __restrict__ e1,
    const float* __restrict__ e2, const float* __restrict__ e3,
    const unsigned short* __restrict__ zpage, bf16x8* smem) {
  constexpr int NFR = BN / 32;
  constexpr int NB = BN / 64;
  constexpr int CPB = 512 + BN * 4;
  const int t = threadIdx.x;
  const int lane = t & 63;
  const int wv = t >> 6;
  const int wr = wv >> 1, wc = wv & 1;

  f32x4 acc[4][NFR];
#pragma unroll
  for (int i = 0; i < 4; i++)
#pragma unroll
    for (int j = 0; j < NFR; j++) acc[i][j] = (f32x4){0.f, 0.f, 0.f, 0.f};

  const unsigned short* Abase[2];
  int aprow[2], apcol[2], akoff[2];
#pragma unroll
  for (int i = 0; i < 2; i++) {
    int c = t + 256 * i;
    int row = (c >> 6) * 16 + (c & 15);
    int koff = ((c >> 4) & 3) * 8;
    akoff[i] = koff;
    int grow = rb + row;
    if constexpr (CIN > 0) {
      int n = grow >> 12, p = grow & 4095;
      aprow[i] = p >> 6;
      apcol[i] = p & 63;
      Abase[i] = A + (size_t)n * 4096 * CIN;
    } else {
      Abase[i] = A + (size_t)grow * K + koff;
    }
  }
  const unsigned short* Bbase[NB];
#pragma unroll
  for (int i = 0; i < NB; i++) {
    int c = t + 256 * i;
    int col = cb + (c >> 6) * 16 + (c & 15);
    int koff = ((c >> 4) & 3) * 8;
    Bbase[i] = (col < Co) ? (Bw + (size_t)col * K + koff) : zpage;
  }
  auto addrA = [&](int i, int kb) -> const unsigned short* {
    if constexpr (CIN > 0) {
      int tap = kb / CIN;
      int ci = (kb & (CIN - 1)) + akoff[i];
      int dy = tap / 3 - 1, dx = tap % 3 - 1;
      int h = aprow[i] + dy, w = apcol[i] + dx;
      if (((unsigned)h < 64u) & ((unsigned)w < 64u))
        return &Abase[i][(size_t)(h * 64 + w) * CIN + ci];
      return zpage;
    } else {
      return Abase[i] + kb;
    }
  };
  auto stage = [&](int buf, int kb) {
    bf16x8* base = &smem[buf * CPB];
    gl_lds16(addrA(0, kb), (void*)&base[t]);
    gl_lds16(addrA(1, kb), (void*)&base[t + 256]);
    gl_lds16((Bbase[0] == zpage) ? zpage : Bbase[0] + kb, (void*)&base[512 + t]);
    if constexpr (NB == 2)
      gl_lds16((Bbase[1] == zpage) ? zpage : Bbase[1] + kb,
               (void*)&base[512 + t + 256]);
  };

  const int nt = KL >> 5;
  stage(0, k0);
  __syncthreads();
  int cur = 0;
  for (int it = 0; it < nt; ++it) {
    if (it + 1 < nt) stage(cur ^ 1, k0 + ((it + 1) << 5));
    const bf16x8* Ab = &smem[cur * CPB];
    const bf16x8* Bb = Ab + 512;
    bf16x8 af[4], bfr[NFR];
#pragma unroll
    for (int mi = 0; mi < 4; mi++) af[mi] = Ab[(wr * 4 + mi) * 64 + lane];
#pragma unroll
    for (int ni = 0; ni < NFR; ni++) bfr[ni] = Bb[(wc * NFR + ni) * 64 + lane];
    __builtin_amdgcn_s_setprio(1);
#pragma unroll
    for (int mi = 0; mi < 4; mi++)
#pragma unroll
      for (int ni = 0; ni < NFR; ni++)
        acc[mi][ni] = __builtin_amdgcn_mfma_f32_16x16x32_bf16(af[mi], bfr[ni],
                                                              acc[mi][ni], 0, 0, 0);
    __builtin_amdgcn_s_setprio(0);
    __syncthreads();
    cur ^= 1;
  }

  // ---- epilogue.  C/D: col = lane&15, row = (lane>>4)*4 + reg
  const int lr = lane & 15, kg4 = (lane >> 4) * 4;
#pragma unroll
  for (int mi = 0; mi < 4; mi++) {
#pragma unroll
    for (int ni = 0; ni < NFR; ni++) {
      int gcol = cb + wc * (BN / 2) + ni * 16 + lr;
      if (gcol >= Co) continue;
      float bval, s = 1.f, tt = 0.f;
      if (EPI == 2 || EPI == 7) bval = 0.f;
      else if (EPI == 5) bval = (gcol < 256) ? bias[gcol] : e0[gcol - 256];
      else bval = bias[gcol];
      if (EPI == 2 || EPI == 3) {
        s = e0[gcol] * rsqrtf(e3[gcol] + EPSV);
        tt = e1[gcol] - e2[gcol] * s;
      }
      if (EPI == 6) {
        int grow0 = rb + wr * 64 + mi * 16 + kg4;
        int n = grow0 >> 12, p0 = grow0 & 4095;
        size_t oix = ((size_t)(n * 256 + gcol)) * 4096 + p0;
        f32x4 xv = *(const f32x4*)&((const float*)e0)[oix];
        const unsigned short* y2p = (const unsigned short*)e1;
        f32x4 ov;
#pragma unroll
        for (int j = 0; j < 4; j++) {
          float y2 = bf2f(y2p[((size_t)(n * 4096 + p0 + j)) * 256 + gcol]);
          ov[j] = acc[mi][ni][j] + bval + xv[j] + y2;
        }
        *(f32x4*)&((float*)outv)[oix] = ov;
        continue;
      }
#pragma unroll
      for (int j = 0; j < 4; j++) {
        int grow = rb + wr * 64 + mi * 16 + kg4 + j;
        float v = acc[mi][ni][j] + bval;
        if (EPI == 2) v = silu_f(v * s + tt);
        if (EPI == 3) v = v * s + tt;
        if (EPI == 4) v = silu_f(v);
        if (EPI == 5) {
          if (gcol < 256)
            ((unsigned short*)outv)[(size_t)grow * 256 + gcol] = f2bf(v);
          else
            ((unsigned short*)e1)[(size_t)grow * 216 + (gcol - 256)] = f2bf(v);
        } else {
          ((unsigned short*)outv)[(size_t)grow * Co + gcol] = f2bf(v);
        }
      }
    }
  }
}

// ---------------------------------------------------------------------------
// GEMM body BK=64, BN=64, BM=128.  4 waves, 64x32 out each, 16 MFMA/iter.
// LDS 24KB/buf, dbuf 48KB.  R14-proven (conv2/outp/pw2 shapes).
// EPI: 2 BN+SiLU->bf16 | 3 bias+BN->bf16 | 6 bias+x+y2 -> NCHW f32
// ---------------------------------------------------------------------------
template <int EPI, int CIN>
__device__ __forceinline__ void gemm_body64(
    int rb, int cb, int k0, int KL,
    const unsigned short* __restrict__ A, const unsigned short* __restrict__ Bw,
    const float* __restrict__ bias, int K, int Co, void* __restrict__ outv,
    const float* __restrict__ e0, const float* __restrict__ e1,
    const float* __restrict__ e2, const float* __restrict__ e3,
    const unsigned short* __restrict__ zpage, bf16x8* smem) {
  constexpr int CPB = 1536;
  const int t = threadIdx.x;
  const int lane = t & 63;
  const int wv = t >> 6;
  const int wr = wv >> 1, wc = wv & 1;

  f32x4 acc[4][2];
#pragma unroll
  for (int i = 0; i < 4; i++)
#pragma unroll
    for (int j = 0; j < 2; j++) acc[i][j] = (f32x4){0.f, 0.f, 0.f, 0.f};

  const unsigned short* Abase[4];
  int aprow[4], apcol[4], akoff[4];
#pragma unroll
  for (int i = 0; i < 4; i++) {
    int c = t + 256 * i;
    int row = (c >> 7) * 16 + (c & 15);
    int koff = ((c >> 6) & 1) * 32 + ((c >> 4) & 3) * 8;
    akoff[i] = koff;
    int grow = rb + row;
    if constexpr (CIN > 0) {
      int n = grow >> 12, p = grow & 4095;
      aprow[i] = p >> 6;
      apcol[i] = p & 63;
      Abase[i] = A + (size_t)n * 4096 * CIN;
    } else {
      Abase[i] = A + (size_t)grow * K + koff;
    }
  }
  const unsigned short* Bbase[2];
#pragma unroll
  for (int i = 0; i < 2; i++) {
    int c = t + 256 * i;
    int col = cb + (c >> 7) * 16 + (c & 15);
    int koff = ((c >> 6) & 1) * 32 + ((c >> 4) & 3) * 8;
    Bbase[i] = (col < Co) ? (Bw + (size_t)col * K + koff) : zpage;
  }
  auto addrA = [&](int i, int kb) -> const unsigned short* {
    if constexpr (CIN > 0) {
      int tap = kb / CIN;
      int ci = (kb & (CIN - 1)) + akoff[i];
      int dy = tap / 3 - 1, dx = tap % 3 - 1;
      int h = aprow[i] + dy, w = apcol[i] + dx;
      if (((unsigned)h < 64u) & ((unsigned)w < 64u))
        return &Abase[i][(size_t)(h * 64 + w) * CIN + ci];
      return zpage;
    } else {
      return Abase[i] + kb;
    }
  };
  auto stage = [&](int buf, int kb) {
    bf16x8* base = &smem[buf * CPB];
#pragma unroll
    for (int i = 0; i < 4; i++)
      gl_lds16(addrA(i, kb), (void*)&base[t + 256 * i]);
    gl_lds16((Bbase[0] == zpage) ? zpage : Bbase[0] + kb,
             (void*)&base[1024 + t]);
    gl_lds16((Bbase[1] == zpage) ? zpage : Bbase[1] + kb,
             (void*)&base[1024 + t + 256]);
  };

  const int nt = KL >> 6;
  stage(0, k0);
  __syncthreads();
  int cur = 0;
  for (int it = 0; it < nt; ++it) {
    if (it + 1 < nt) stage(cur ^ 1, k0 + ((it + 1) << 6));
    const bf16x8* Ab = &smem[cur * CPB];
    const bf16x8* Bb = Ab + 1024;
    __builtin_amdgcn_s_setprio(1);
#pragma unroll
    for (int ks = 0; ks < 2; ks++) {
      bf16x8 af[4], bfr[2];
#pragma unroll
      for (int mi = 0; mi < 4; mi++)
        af[mi] = Ab[((wr * 4 + mi) * 2 + ks) * 64 + lane];
#pragma unroll
      for (int ni = 0; ni < 2; ni++)
        bfr[ni] = Bb[((wc * 2 + ni) * 2 + ks) * 64 + lane];
#pragma unroll
      for (int mi = 0; mi < 4; mi++)
#pragma unroll
        for (int ni = 0; ni < 2; ni++)
          acc[mi][ni] = __builtin_amdgcn_mfma_f32_16x16x32_bf16(
              af[mi], bfr[ni], acc[mi][ni], 0, 0, 0);
    }
    __builtin_amdgcn_s_setprio(0);
    __syncthreads();
    cur ^= 1;
  }

  const int lr = lane & 15, kg4 = (lane >> 4) * 4;
#pragma unroll
  for (int mi = 0; mi < 4; mi++) {
#pragma unroll
    for (int ni = 0; ni < 2; ni++) {
      int gcol = cb + wc * 32 + ni * 16 + lr;
      if (gcol >= Co) continue;
      float bval, s = 1.f, tt = 0.f;
      if (EPI == 2) bval = 0.f;
      else bval = bias[gcol];
      if (EPI == 2 || EPI == 3) {
        s = e0[gcol] * rsqrtf(e3[gcol] + EPSV);
        tt = e1[gcol] - e2[gcol] * s;
      }
      if (EPI == 6) {
        int grow0 = rb + wr * 64 + mi * 16 + kg4;
        int n = grow0 >> 12, p0 = grow0 & 4095;
        size_t oix = ((size_t)(n * 256 + gcol)) * 4096 + p0;
        f32x4 xv = *(const f32x4*)&((const float*)e0)[oix];
        const unsigned short* y2p = (const unsigned short*)e1;
        f32x4 ov;
#pragma unroll
        for (int j = 0; j < 4; j++) {
          float y2 = bf2f(y2p[((size_t)(n * 4096 + p0 + j)) * 256 + gcol]);
          ov[j] = acc[mi][ni][j] + bval + xv[j] + y2;
        }
        *(f32x4*)&((float*)outv)[oix] = ov;
        continue;
      }
#pragma unroll
      for (int j = 0; j < 4; j++) {
        int grow = rb + wr * 64 + mi * 16 + kg4 + j;
        float v = acc[mi][ni][j] + bval;
        if (EPI == 2) v = silu_f(v * s + tt);
        if (EPI == 3) v = v * s + tt;
        ((unsigned short*)outv)[(size_t)grow * Co + gcol] = f2bf(v);
      }
    }
  }
}

// ---------------------------------------------------------------------------
// DCNv4 core body v3: 8 pixels/block, lanes carry 8 channels; om bf16.
// ---------------------------------------------------------------------------
__device__ __forceinline__ void dcn_body(
    int bid, const unsigned short* __restrict__ value,
    const unsigned short* __restrict__ om, unsigned short* __restrict__ out,
    void* smemraw) {
  f32x4* wgt = (f32x4*)smemraw;
  i32x4* adr = (i32x4*)((char*)smemraw + 576 * 16);
  const int n = bid >> 9;
  const int p0 = (bid & 511) * 8;
  const int t = threadIdx.x;

  for (int idx = t; idx < 576; idx += 256) {
    int pi = idx / 72;
    int gk = idx - pi * 72;
    int g = gk / 9, k = gk - g * 9;
    int p = p0 + pi;
    int h0 = p >> 6, w0 = p & 63;
    const unsigned short* omp = om + ((size_t)(n * 4096 + p)) * 216 + g * 27;
    float ox = bf2f(omp[2 * k]), oy = bf2f(omp[2 * k + 1]);
    float mk = bf2f(omp[18 + k]);
    float px = (float)(w0 + (k % 3) - 1) + ox;
    float py = (float)(h0 + (k / 3) - 1) + oy;
    float x0f = floorf(px), y0f = floorf(py);
    float lx = px - x0f, ly = py - y0f;
    int x0 = (int)x0f, y0 = (int)y0f;
    int x1 = x0 + 1, y1 = y0 + 1;
    bool vx0 = (unsigned)x0 < 64u, vx1 = (unsigned)x1 < 64u;
    bool vy0 = (unsigned)y0 < 64u, vy1 = (unsigned)y1 < 64u;
    int cx0 = min(max(x0, 0), 63), cx1 = min(max(x1, 0), 63);
    int cy0 = min(max(y0, 0), 63), cy1 = min(max(y1, 0), 63);
    f32x4 w4;
    w4[0] = (1.f - ly) * (1.f - lx) * mk * (float)(vy0 && vx0);
    w4[1] = (1.f - ly) * lx * mk * (float)(vy0 && vx1);
    w4[2] = ly * (1.f - lx) * mk * (float)(vy1 && vx0);
    w4[3] = ly * lx * mk * (float)(vy1 && vx1);
    i32x4 a4;
    a4[0] = (cy0 * 64 + cx0) * 256;
    a4[1] = (cy0 * 64 + cx1) * 256;
    a4[2] = (cy1 * 64 + cx0) * 256;
    a4[3] = (cy1 * 64 + cx1) * 256;
    wgt[idx] = w4;
    adr[idx] = a4;
  }
  __syncthreads();

  const int pi = t >> 5;
  const int g = (t >> 2) & 7;
  const int l = t & 3;
  const int p = p0 + pi;
  const unsigned short* vb = value + ((size_t)n * 4096) * 256 + g * 32 + l * 8;
  const int bix = (pi * 8 + g) * 9;
  float a[8] = {0.f, 0.f, 0.f, 0.f, 0.f, 0.f, 0.f, 0.f};
#pragma unroll
  for (int k = 0; k < 9; k++) {
    f32x4 wv = wgt[bix + k];
    i32x4 av = adr[bix + k];
    us8 q0 = *(const us8*)(vb + av[0]);
    us8 q1 = *(const us8*)(vb + av[1]);
    us8 q2 = *(const us8*)(vb + av[2]);
    us8 q3 = *(const us8*)(vb + av[3]);
#pragma unroll
    for (int j = 0; j < 8; j++)
      a[j] += wv[0] * bf2f(q0[j]) + wv[1] * bf2f(q1[j]) +
              wv[2] * bf2f(q2[j]) + wv[3] * bf2f(q3[j]);
  }
  us8 o;
#pragma unroll
  for (int j = 0; j < 8; j++) o[j] = f2bf(a[j]);
  *(us8*)&out[((size_t)(n * 4096 + p)) * 256 + g * 32 + l * 8] = o;
}

// ---------------------------------------------------------------------------
// PREP (1624 blocks): xt transpose (0..1023) + wc1 cvt (1024..1151) +
// wval/wom cvt (1152..1623).
// ---------------------------------------------------------------------------
__global__ __launch_bounds__(256) void prep_k(
    const float* __restrict__ x, unsigned short* __restrict__ xt,
    const float* __restrict__ c1, unsigned short* __restrict__ o1,
    const float* __restrict__ a0, unsigned short* __restrict__ b0,
    const float* __restrict__ a1, unsigned short* __restrict__ b1,
    uint32* __restrict__ zp) {
  __shared__ float lds[64][65];
  int b = blockIdx.x;
  const int t = threadIdx.x;
  if (b == 0 && t < 32) zp[t] = 0u;
  if (b < 1024) {
    const int p0 = (b & 63) * 64, c0 = ((b >> 6) & 3) * 64, n = b >> 8;
    const int pp = t & 63, ccb = t >> 6;
    const float* xb = x + ((size_t)n * 256 + c0) * 4096 + p0;
#pragma unroll
    for (int i = 0; i < 16; i++) {
      int cc = ccb * 16 + i;
      lds[pp][cc] = xb[(size_t)cc * 4096 + pp];
    }
    __syncthreads();
#pragma unroll
    for (int i = 0; i < 2; i++) {
      int pp2 = (t >> 3) + i * 32;
      int c8 = (t & 7) * 8;
      us8 v;
#pragma unroll
      for (int j = 0; j < 8; j++) v[j] = f2bf(lds[pp2][c8 + j]);
      *(us8*)&xt[((size_t)(n * 4096 + p0 + pp2)) * 256 + c0 + c8] = v;
    }
    return;
  }
  if (b < 1152) {
    int idx = (b - 1024) * 256 + t;
    int co = idx >> 8, ci = idx & 255;
    const float* src = c1 + (size_t)(co * 256 + ci) * 9;
#pragma unroll
    for (int tap = 0; tap < 9; tap++)
      o1[(size_t)(co * 9 + tap) * 256 + ci] = f2bf(src[tap]);
    return;
  }
  int idx = (b - 1152) * 256 + t;
  if (idx < 65536) b0[idx] = f2bf(a0[idx]);
  else if (idx < 120832) b1[idx - 65536] = f2bf(a1[idx - 65536]);
}

// ---------------------------------------------------------------------------
// S1 (1600 blocks): 0..511 conv1 split-K x4 (xsr within range),
// 512..1023 val/om (xsr), 1024..1471 plain cvts, 1472..1599 wc2 cvt.
// ---------------------------------------------------------------------------
__global__ __launch_bounds__(256) void fused_s1(
    const unsigned short* __restrict__ xt,
    const unsigned short* __restrict__ wc1, unsigned short* __restrict__ part,
    const unsigned short* __restrict__ wval, const float* __restrict__ val_b,
    const float* __restrict__ om_b, unsigned short* __restrict__ omf,
    unsigned short* __restrict__ valt, const unsigned short* __restrict__ zpage,
    const float* __restrict__ outp_w, unsigned short* __restrict__ woutp,
    const float* __restrict__ pw1_w, unsigned short* __restrict__ wpw1,
    const float* __restrict__ pw2_w, unsigned short* __restrict__ wpw2,
    const float* __restrict__ cv2_w, unsigned short* __restrict__ wc2) {
  __shared__ bf16x8 smem[2048];
  int b = blockIdx.x;
  const int t = threadIdx.x;
  if (b < 512) {
    int l = xsr(b, 512);                   // XCD-contiguous M within conv1
    int s = l >> 7, mt = l & 127;
    gemm_body<7, 256, 128>(mt * 128, 0, s * 576, 576, xt, wc1, nullptr, 2304,
                           128, part + (size_t)s * 2097152, nullptr, nullptr,
                           nullptr, nullptr, zpage, smem);
  } else if (b < 1024) {
    int l = xsr(b - 512, 512);             // col-tiles of same M grouped
    gemm_body<5, 0, 128>((l >> 2) * 128, (l & 3) * 128, 0, 256, xt, wval, val_b,
                         256, 472, valt, om_b, (const float*)(const void*)omf,
                         nullptr, nullptr, zpage, smem);
  } else if (b < 1472) {
    int idx4 = (b - 1024) * 1024 + t * 4;
    const float* s;
    unsigned short* d;
    int off;
    if (idx4 < 65536)       { s = outp_w; d = woutp; off = idx4; }
    else if (idx4 < 262144) { s = pw1_w;  d = wpw1;  off = idx4 - 65536; }
    else                    { s = pw2_w;  d = wpw2;  off = idx4 - 262144; }
    f32x4 v = *(const f32x4*)&s[off];
    us4 o;
#pragma unroll
    for (int j = 0; j < 4; j++) o[j] = f2bf(v[j]);
    *(us4*)&d[off] = o;
  } else {
    int idx = (b - 1472) * 256 + t;
    int co = idx >> 7, ci = idx & 127;
    const float* src = cv2_w + (size_t)(co * 128 + ci) * 9;
#pragma unroll
    for (int tap = 0; tap < 9; tap++)
      wc2[(size_t)(co * 9 + tap) * 128 + ci] = f2bf(src[tap]);
  }
}

// ---------------------------------------------------------------------------
// R (3072 blocks): 0..1023 y1 reduce+BN+SiLU, 1024..3071 dcn v3 (xsr).
// ---------------------------------------------------------------------------
__global__ __launch_bounds__(256) void fused_r(
    const unsigned short* __restrict__ part, const float* __restrict__ g1,
    const float* __restrict__ bb1, const float* __restrict__ m1,
    const float* __restrict__ v1, unsigned short* __restrict__ y1t,
    const unsigned short* __restrict__ valt, const unsigned short* __restrict__ omf,
    unsigned short* __restrict__ dcnt) {
  __shared__ char rsm[18432];
  int b = blockIdx.x;
  if (b < 1024) {
    int g = b * 256 + threadIdx.x;
    int grow = g >> 4;
    int co8 = (g & 15) << 3;
    size_t base = (size_t)grow * 128 + co8;
    float sum[8] = {0.f, 0.f, 0.f, 0.f, 0.f, 0.f, 0.f, 0.f};
#pragma unroll
    for (int s = 0; s < 4; s++) {
      us8 pv = *(const us8*)&part[base + (size_t)s * 2097152];
#pragma unroll
      for (int j = 0; j < 8; j++) sum[j] += bf2f(pv[j]);
    }
    us8 o;
#pragma unroll
    for (int j = 0; j < 8; j++) {
      int co = co8 + j;
      float sc = g1[co] * rsqrtf(v1[co] + EPSV);
      float tt = bb1[co] - m1[co] * sc;
      o[j] = f2bf(silu_f(sum[j] * sc + tt));
    }
    *(us8*)&y1t[base] = o;
  } else {
    dcn_body(xsr(b - 1024, 2048), valt, omf, dcnt, (void*)rsm);
  }
}

// ---------------------------------------------------------------------------
// S2 (512 blocks, BK=64): outp only (xsr: 4 col-tiles of same M grouped).
// ---------------------------------------------------------------------------
__global__ __launch_bounds__(256) void s2_outp(
    const unsigned short* __restrict__ dcnt, const unsigned short* __restrict__ woutp,
    const float* __restrict__ outp_b, const float* __restrict__ g3,
    const float* __restrict__ bb3, const float* __restrict__ m3,
    const float* __restrict__ v3, unsigned short* __restrict__ d1t,
    const unsigned short* __restrict__ zpage) {
  __shared__ bf16x8 smem[3072];
  int l = xsr(blockIdx.x, 512);
  gemm_body64<3, 0>((l >> 2) * 128, (l & 3) * 64, 0, 256, dcnt, woutp,
                    outp_b, 256, 256, d1t, g3, bb3, m3, v3, zpage, smem);
}

// ---------------------------------------------------------------------------
// P (1280 blocks): 0..511 conv2 (xsr within range), 512..1279 pw1 (xsr).
// ---------------------------------------------------------------------------
__global__ __launch_bounds__(256) void fused_p(
    const unsigned short* __restrict__ y1t,
    const unsigned short* __restrict__ wc2, const float* __restrict__ g2,
    const float* __restrict__ bb2, const float* __restrict__ m2,
    const float* __restrict__ v2, unsigned short* __restrict__ y2t,
    const unsigned short* __restrict__ d1t, const unsigned short* __restrict__ wpw1,
    const float* __restrict__ pw1_b, unsigned short* __restrict__ p1t,
    const unsigned short* __restrict__ zpage) {
  __shared__ bf16x8 smem[3072];
  int b = blockIdx.x;
  if (b < 512) {
    int l = xsr(b, 512);
    gemm_body64<2, 128>((l >> 2) * 128, (l & 3) * 64, 0, 1152, y1t, wc2,
                        nullptr, 1152, 256, y2t, g2, bb2, m2, v2, zpage, smem);
  } else {
    int l = xsr(b - 512, 768);
    gemm_body<4, 0, 128>((l / 6) * 128, (l % 6) * 128, 0, 256, d1t, wpw1,
                         pw1_b, 256, 768, p1t, nullptr, nullptr, nullptr,
                         nullptr, zpage, smem);
  }
}

// ---------------------------------------------------------------------------
// pw2 + residual (512 blocks, BK=64, EPI 6, xsr).
// ---------------------------------------------------------------------------
__global__ __launch_bounds__(256) void pw2_k(
    const unsigned short* __restrict__ p1t, const unsigned short* __restrict__ wpw2,
    const float* __restrict__ pw2_b, const float* __restrict__ x,
    const unsigned short* __restrict__ y2t, float* __restrict__ out,
    const unsigned short* __restrict__ zpage) {
  __shared__ bf16x8 smem[3072];
  int l = xsr(blockIdx.x, 512);
  gemm_body64<6, 0>((l >> 2) * 128, (l & 3) * 64, 0, 768, p1t, wpw2, pw2_b,
                    768, 256, out, x, (const float*)(const void*)y2t,
                    nullptr, nullptr, zpage, smem);
}

// ---------------------------------------------------------------------------
extern "C" void kernel_launch(void* const* d_in, const int* in_sizes, int n_in,
                              void* d_out, int out_size, void* d_ws,
                              size_t ws_size, hipStream_t stream) {
  const float* x      = (const float*)d_in[0];
  const float* cv1_w  = (const float*)d_in[1];
  const float* cv1_g  = (const float*)d_in[2];
  const float* cv1_b  = (const float*)d_in[3];
  const float* cv1_m  = (const float*)d_in[4];
  const float* cv1_v  = (const float*)d_in[5];
  const float* cv2_w  = (const float*)d_in[6];
  const float* cv2_g  = (const float*)d_in[7];
  const float* cv2_b  = (const float*)d_in[8];
  const float* cv2_m  = (const float*)d_in[9];
  const float* cv2_v  = (const float*)d_in[10];
  const float* val_w  = (const float*)d_in[11];
  const float* val_b  = (const float*)d_in[12];
  const float* om_w   = (const float*)d_in[13];
  const float* om_b   = (const float*)d_in[14];
  const float* outp_w = (const float*)d_in[15];
  const float* outp_b = (const float*)d_in[16];
  const float* bn3_g  = (const float*)d_in[17];
  const float* bn3_b  = (const float*)d_in[18];
  const float* bn3_m  = (const float*)d_in[19];
  const float* bn3_v  = (const float*)d_in[20];
  const float* pw1_w  = (const float*)d_in[21];
  const float* pw1_b  = (const float*)d_in[22];
  const float* pw2_w  = (const float*)d_in[23];
  const float* pw2_b  = (const float*)d_in[24];
  float* out = (float*)d_out;

  char* w = (char*)d_ws;
  auto alloc = [&](size_t bytes) {
    char* p = w;
    w += (bytes + 255) & ~(size_t)255;
    return p;
  };
  unsigned short* xt    = (unsigned short*)alloc(16384ull * 256 * 2);
  unsigned short* y1t   = (unsigned short*)alloc(16384ull * 128 * 2);
  unsigned short* y2t   = (unsigned short*)alloc(16384ull * 256 * 2);
  unsigned short* valt  = (unsigned short*)alloc(16384ull * 256 * 2);
  unsigned short* omf   = (unsigned short*)alloc(16384ull * 216 * 2);
  unsigned short* dcnt  = (unsigned short*)alloc(16384ull * 256 * 2);
  unsigned short* d1t   = (unsigned short*)alloc(16384ull * 256 * 2);
  unsigned short* p1t   = (unsigned short*)alloc(16384ull * 768 * 2);
  unsigned short* part = d1t;   // conv1 partials alias d1t+p1t
  unsigned short* wc1   = (unsigned short*)alloc(128ull * 2304 * 2);
  unsigned short* wc2   = (unsigned short*)alloc(256ull * 1152 * 2);
  unsigned short* wval  = (unsigned short*)alloc(256ull * 256 * 2);
  unsigned short* wom   = (unsigned short*)alloc(216ull * 256 * 2);
  unsigned short* woutp = (unsigned short*)alloc(256ull * 256 * 2);
  unsigned short* wpw1  = (unsigned short*)alloc(768ull * 256 * 2);
  unsigned short* wpw2  = (unsigned short*)alloc(256ull * 768 * 2);
  unsigned short* zpage = (unsigned short*)alloc(256);

  prep_k<<<1624, 256, 0, stream>>>(x, xt, cv1_w, wc1, val_w, wval, om_w, wom,
                                   (uint32*)zpage);

  fused_s1<<<1600, 256, 0, stream>>>(xt, wc1, part, wval, val_b, om_b, omf,
                                     valt, zpage, outp_w, woutp, pw1_w, wpw1,
                                     pw2_w, wpw2, cv2_w, wc2);

  fused_r<<<3072, 256, 0, stream>>>(part, cv1_g, cv1_b, cv1_m, cv1_v, y1t,
                                    valt, omf, dcnt);

  s2_outp<<<512, 256, 0, stream>>>(dcnt, woutp, outp_b, bn3_g, bn3_b, bn3_m,
                                   bn3_v, d1t, zpage);

  fused_p<<<1280, 256, 0, stream>>>(y1t, wc2, cv2_g, cv2_b, cv2_m, cv2_v, y2t,
                                    d1t, wpw1, pw1_b, p1t, zpage);

  pw2_k<<<512, 256, 0, stream>>>(p1t, wpw2, pw2_b, x, y2t, out, zpage);
}